// Round 6
// baseline (263.171 us; speedup 1.0000x reference)
//
#include <hip/hip_runtime.h>
#include <hip/hip_bf16.h>

#define B_ 2
#define N_ 4096
#define M_ 12288
#define K_ 64
#define SH_ 32
#define H_ 64
#define GK_ 8
#define NC_ 200

#define KCAP 128       // knn candidate cap (E=40, +13 sigma)
#define BCAP2 48       // sampler boundary cap
#define SCAP 144       // sampler stored-candidate cap (E=96, +4.9 sigma; overflow -> slow path)
#define MG_ 0.01f      // window safety margin (rad)
#define C256_ 81.48733086f   // 256/pi (threshold grid, theta-keyed)

// 2-D sort: 4 coarse theta bands x 64 phi buckets = 256 buckets (NBKT unchanged vs 1-D)
#define TB_ 4
#define PB_ 64
#define CTB_ 1.27323954f     // 4/pi
#define CPB_ 10.18591636f    // 64/(2pi)
#define TWO_PI_ 6.28318530718f
#define INV2PI_ 0.15915494309f

static __device__ __forceinline__ unsigned f2key(float f) {
  unsigned b = __float_as_uint(f);
  return (b & 0x80000000u) ? ~b : (b | 0x80000000u);
}
static __device__ __forceinline__ float key2f(unsigned u) {
  unsigned b = (u & 0x80000000u) ? (u & 0x7fffffffu) : ~u;
  return __uint_as_float(b);
}
static __device__ __forceinline__ unsigned long long shflxor64(unsigned long long x, int m) {
  unsigned lo = (unsigned)x, hi = (unsigned)(x >> 32);
  lo = (unsigned)__shfl_xor((int)lo, m);
  hi = (unsigned)__shfl_xor((int)hi, m);
  return ((unsigned long long)hi << 32) | lo;
}
// keys carry SORTED positions (known from loop counter; no index load in scans)
static __device__ __forceinline__ unsigned long long kpack(float s, int pos) {
  return ((unsigned long long)f2key(s) << 14) | (unsigned)(16383 - pos);
}
static __device__ __forceinline__ unsigned long long spack(float c, int pos) {
  return ((unsigned long long)f2key(c) << 12) | (unsigned)(4095 - pos);
}
static __device__ __forceinline__ int thbkt(float th) {     // 256-grid (thresholds)
  int b = (int)(th * C256_);
  return b < 0 ? 0 : (b > 255 ? 255 : b);
}
static __device__ __forceinline__ int tband(float th) {     // coarse band
  int b = (int)(th * CTB_);
  return b < 0 ? 0 : (b > TB_-1 ? TB_-1 : b);
}
static __device__ __forceinline__ int pbkt(float ph) {      // phi col
  int b = (int)(ph * CPB_);
  return b < 0 ? 0 : (b > PB_-1 ? PB_-1 : b);
}
static __device__ __forceinline__ float clamp1(float x) { return fminf(1.f, fmaxf(-1.f, x)); }
static __device__ __forceinline__ float rdlane(float v, int c) {
  return __uint_as_float((unsigned)__builtin_amdgcn_readlane((int)__float_as_uint(v), c));
}

// phi-window union for a query pair (proven in vG): returns (pbl, nb); nb==PB_ => full ring.
static __device__ __forceinline__ void phi_window(
    float thp0, float php0, float al0, float thp1, float php1, float al1,
    int& pbl, int& nb)
{
  float sp0 = sinf(thp0), sp1 = sinf(thp1);
  float sa0 = sinf(fminf(al0 + MG_, 1.5707f));
  float sa1 = sinf(fminf(al1 + MG_, 1.5707f));
  bool full = (sa0 >= sp0 * 0.9999f) || (sa1 >= sp1 * 0.9999f);
  if (!full) {
    float dp0 = asinf(fminf(sa0 / sp0, 1.f)) + MG_;
    float dp1 = asinf(fminf(sa1 / sp1, 1.f)) + MG_;
    float d = php1 - php0;
    d -= floorf(d * INV2PI_ + 0.5f) * TWO_PI_;          // wrap to [-pi, pi]
    float lo = fminf(-dp0, d - dp1), hi = fmaxf(dp0, d + dp1);
    float wdt = hi - lo;
    if (wdt >= TWO_PI_ * 0.95f) full = true;
    else {
      float a0 = php0 + lo;
      a0 -= floorf(a0 * INV2PI_) * TWO_PI_;             // [0, 2pi)
      pbl = (int)(a0 * CPB_);
      pbl = pbl < 0 ? 0 : (pbl > PB_-1 ? PB_-1 : pbl);
      nb = (int)(wdt * CPB_) + 2;                       // ceil + quant slack
      if (nb > PB_) nb = PB_;
    }
  }
  if (full) { pbl = 0; nb = PB_; }
}

// ---------------- sentinel ----------------
__global__ __launch_bounds__(256) void sentinel_vK(float* out, int n, float val) {
  int t = blockIdx.x * 256 + threadIdx.x;
  if (t < n) out[t] = val;
}

// ---------------- prep + GRID thresholds (257-pt theta grid) + 2-D bucket hist ----------------
#define GRIDB_ 129     // 129 blocks x 4 waves = 516 jobs >= 2*257
#define PREPN_ (M_ + B_*N_ + B_*H_)
#define PREPB_ ((PREPN_ + 255)/256)

__global__ __launch_bounds__(256) void prep_vK(
    const float* __restrict__ xxx, const float* __restrict__ pix,
    float4* __restrict__ r_pix, float4* __restrict__ r_los, float* __restrict__ gf,
    float* __restrict__ kthrG, float* __restrict__ cthrG, unsigned* __restrict__ cnt)
{
  const float PI = 3.14159265358979f;
  if ((int)blockIdx.x < GRIDB_) {
    int gid  = blockIdx.x*4 + (threadIdx.x >> 6);
    if (gid >= 514) return;
    int lane = threadIdx.x & 63;
    int tgt  = (gid >= 257) ? 1 : 0;
    int gp   = gid - tgt*257;
    float thp = (float)gp * (PI/256.f);
    float cp = cosf(thp), sp = fmaxf(sinf(thp), 1e-6f);
    float thq = ((float)lane + 0.5f) * (PI/64.f);
    float sq = sinf(thq), cq = cosf(thq);
    float rinv = 1.0f / (sq * sp);
    // E targets: sampler 96 of N, knn 40 of M (top-K invariant to threshold while count>=K)
    float At = tgt ? (2.f*PI*PI*96.f/(float)N_) : (2.f*PI*PI*40.f/(float)M_);
    float lo = 1e-3f, hi = 3.1414f;
    for (int it = 0; it < 12; ++it) {
      float al = 0.5f*(lo + hi);
      float ca = cosf(al);
      float arg = clamp1((ca - cq*cp) * rinv);
      float ax = fabsf(arg);
      float ac = sqrtf(fmaxf(0.f, 1.f - ax)) *
                 fmaf(ax, fmaf(ax, fmaf(ax, -0.0187293f, 0.0742610f), -0.2121144f), 1.5707288f);
      ac = (arg < 0.f) ? (PI - ac) : ac;
      float S = ac;
      #pragma unroll
      for (int off = 32; off; off >>= 1) S += __shfl_xor(S, off);
      float A = 2.f * S * (PI/64.f);
      if (A < At) lo = al; else hi = al;
    }
    if (lane == 0) {
      float chv = cosf(hi);
      if (tgt) cthrG[gp] = chv - 1e-5f;
      else     kthrG[gp] = 2.f*chv - 1.00002f;
    }
  } else {
    int tid = ((int)blockIdx.x - GRIDB_)*256 + threadIdx.x;
    if (tid < M_) {
      float th = pix[2*tid], ph = pix[2*tid+1];
      float st = sinf(th);
      float x = st*cosf(ph), y = st*sinf(ph), z = cosf(th);
      r_pix[tid] = make_float4(x, y, z, x*x + y*y + z*z);
      atomicAdd(&cnt[tband(th)*PB_ + pbkt(ph)], 1u);
    }
    int t2 = tid - M_;
    if (t2 >= 0 && t2 < B_*N_) {
      int b = t2 >> 12, n = t2 & (N_-1);
      const float* xb = xxx + b*3*N_;
      float th = xb[n], ph = xb[N_+n], ft = xb[2*N_+n];
      float st = sinf(th);
      r_los[t2] = make_float4(st*cosf(ph), st*sinf(ph), cosf(th), ft);
      atomicAdd(&cnt[256 + b*256 + tband(th)*PB_ + pbkt(ph)], 1u);
    }
    int t3 = tid - M_ - B_*N_;
    if (t3 >= 0 && t3 < B_*H_) gf[t3] = 0.0f;
  }
}

// ---------------- scan (unchanged: 3 arrays of 256 buckets) ----------------
__global__ __launch_bounds__(256) void scan_vK(
    const unsigned* __restrict__ cnt, int* __restrict__ pstart, int* __restrict__ lstart,
    unsigned* __restrict__ pcur, unsigned* __restrict__ lcur)
{
  __shared__ unsigned buf[256];
  const int t = threadIdx.x;
  for (int arr = 0; arr < 3; ++arr) {
    unsigned v = cnt[arr*256 + t];
    buf[t] = v;
    __syncthreads();
    for (int off = 1; off < 256; off <<= 1) {
      unsigned o = (t >= off) ? buf[t - off] : 0u;
      __syncthreads();
      buf[t] += o;
      __syncthreads();
    }
    unsigned incl = buf[t], excl = incl - v;
    if (arr == 0) {
      pstart[t] = (int)excl; if (t == 255) pstart[256] = (int)incl;
      pcur[t] = excl;
    } else {
      int b = arr - 1;
      lstart[b*257 + t] = (int)excl; if (t == 255) lstart[b*257 + 256] = (int)incl;
      lcur[b*256 + t] = excl;
    }
    __syncthreads();
  }
}

// ---------------- scatter (2-D bucket) ----------------
__global__ __launch_bounds__(256) void scatter_vK(
    const float* __restrict__ xxx, const float* __restrict__ pix,
    const float4* __restrict__ r_pix, const float4* __restrict__ r_los,
    unsigned* __restrict__ pcur, unsigned* __restrict__ lcur,
    float4* __restrict__ spix, int* __restrict__ sjdx,
    float4* __restrict__ slos)
{
  int tid = blockIdx.x * 256 + threadIdx.x;
  if (tid < M_) {
    int bkt = tband(pix[2*tid])*PB_ + pbkt(pix[2*tid+1]);
    unsigned pos = atomicAdd(&pcur[bkt], 1u);
    spix[pos] = r_pix[tid];
    sjdx[pos] = tid;
  } else {
    int t2 = tid - M_;
    if (t2 < B_*N_) {
      int b = t2 >> 12, n = t2 & (N_-1);
      const float* xb = xxx + b*3*N_;
      int bkt = tband(xb[n])*PB_ + pbkt(xb[N_+n]);
      unsigned pos = atomicAdd(&lcur[b*256 + bkt], 1u);
      slos[b*N_ + pos] = r_los[t2];
    }
  }
}

// ---------------- sampler vK: coarse 2-D window (1-2 bands x phi segments), pos-keys;
// ---------------- slow paths on full-band supersets (predicate makes superset-scan exact) -----
__global__ __launch_bounds__(512) void sampler_vK(
    const float* __restrict__ pix,
    const float4* __restrict__ spix, const int* __restrict__ sjdx,
    const float4* __restrict__ slos,
    const int* __restrict__ lstart,
    const float* __restrict__ cthrG,
    const float* __restrict__ aw1, const float* __restrict__ ab1,
    const float* __restrict__ aw2, const float* __restrict__ ab2,
    float* __restrict__ pooled)
{
  __shared__ unsigned long long cand[16][SCAP];     // 18 KB
  __shared__ unsigned long long selKey[16][K_];     // 8 KB
  __shared__ unsigned long long bndK[16][BCAP2];    // 6 KB
  __shared__ unsigned hist[16][64];                 // 4 KB   -> 36 KB, 4 blocks/CU

  const int tid = threadIdx.x, wv = tid >> 6, lane = tid & 63;
  const int b  = blockIdx.y;
  const int srow0 = blockIdx.x*16 + wv*2, srow1 = srow0 + 1;
  const int r0 = wv*2, r1 = r0 + 1;
  const int m0 = sjdx[srow0], m1 = sjdx[srow1];
  const float4 p0 = spix[srow0], p1 = spix[srow1];
  const float thp0 = pix[2*m0], thp1 = pix[2*m1];
  const float php0 = pix[2*m0+1], php1 = pix[2*m1+1];
  const int g0 = thbkt(thp0), g1 = thbkt(thp1);
  const float th0 = fminf(cthrG[g0], cthrG[g0+1]);
  const float th1 = fminf(cthrG[g1], cthrG[g1+1]);
  const float inv0 = 63.999f / (1.000001f - th0);
  const float inv1 = 63.999f / (1.000001f - th1);
  const float4* sl = slos + b * N_;
  const int* ls = lstart + b * 257;
  const unsigned long long ltm = (1ull << lane) - 1ull;

  // union window: coarse bands + phi bucket window
  const float al0 = acosf(clamp1(th0)), al1 = acosf(clamp1(th1));
  int rlo, rhi, pbl, nb;
  {
    rlo = tband(fminf(thp0 - al0, thp1 - al1) - MG_);
    rhi = tband(fmaxf(thp0 + al0, thp1 + al1) + MG_);
    phi_window(thp0, php0, al0, thp1, php1, al1, pbl, nb);
  }

  // single pass over band x phi segments: dot, predicate, compact both rows (pos-keys)
  unsigned cnt0 = 0, cnt1 = 0;
  {
    auto doChunk = [&](int base, int e) {
      int pos = base + lane;
      bool act = pos < e;
      float c0 = -2.f, c1 = -2.f;
      if (act) {
        float4 v = sl[pos];
        c0 = clamp1(v.x*p0.x + v.y*p0.y + v.z*p0.z);
        c1 = clamp1(v.x*p1.x + v.y*p1.y + v.z*p1.z);
      }
      bool pr0 = c0 > th0, pr1 = c1 > th1;
      unsigned long long mk0 = __ballot(pr0);
      if (mk0) {
        unsigned off = (unsigned)__popcll(mk0 & ltm);
        if (pr0 && cnt0 + off < SCAP) cand[r0][cnt0 + off] = spack(c0, pos);
        cnt0 += (unsigned)__popcll(mk0);
      }
      unsigned long long mk1 = __ballot(pr1);
      if (mk1) {
        unsigned off = (unsigned)__popcll(mk1 & ltm);
        if (pr1 && cnt1 + off < SCAP) cand[r1][cnt1 + off] = spack(c1, pos);
        cnt1 += (unsigned)__popcll(mk1);
      }
    };
    for (int band = rlo; band <= rhi; ++band) {
      const int rb = band * PB_;
      if (pbl + nb <= PB_) {
        int s = ls[rb + pbl], e = ls[rb + pbl + nb];
        for (int base = s; base < e; base += 64) doChunk(base, e);
      } else {
        int s1 = ls[rb + pbl], e1 = ls[rb + PB_];
        for (int base = s1; base < e1; base += 64) doChunk(base, e1);
        int s2 = ls[rb], e2 = ls[rb + pbl + nb - PB_];
        for (int base = s2; base < e2; base += 64) doChunk(base, e2);
      }
    }
  }

  for (int rr = 0; rr < 2; ++rr) {
    const int r = (rr == 0) ? r0 : r1;
    const int m = (rr == 0) ? m0 : m1;
    const float4 p = (rr == 0) ? p0 : p1;
    const float thp = (rr == 0) ? thp0 : thp1;
    const float thg = (rr == 0) ? th0 : th1;
    const float invg = (rr == 0) ? inv0 : inv1;
    unsigned cn = (rr == 0) ? cnt0 : cnt1;
    bool fin = false;

    // fast path: all candidates captured in LDS -> select without touching global
    if (cn >= (unsigned)K_ && cn <= (unsigned)SCAP) {
      hist[r][lane] = 0u;
      for (int i = lane; i < (int)cn; i += 64) {
        float c = key2f((unsigned)(cand[r][i] >> 12));
        atomicAdd(&hist[r][(int)((c - thg) * invg)], 1u);
      }
      unsigned g = hist[r][lane], s = g;
      #pragma unroll
      for (int off = 1; off < 64; off <<= 1) {
        unsigned t2 = (unsigned)__shfl_down((int)s, off);
        s += (lane + off < 64) ? t2 : 0u;
      }
      unsigned snext = s - g;
      unsigned packed = (s >= K_ && snext < K_) ? (((unsigned)(lane+1) << 16) | snext) : 0u;
      #pragma unroll
      for (int off = 32; off; off >>= 1) {
        unsigned o = (unsigned)__shfl_xor((int)packed, off);
        packed = packed > o ? packed : o;
      }
      const int t = (int)(packed >> 16) - 1;
      const unsigned chi = packed & 0xFFFFu;
      const unsigned need = K_ - chi;

      unsigned hiC = 0, bdC = 0;
      for (int i0 = 0; i0 < (int)cn; i0 += 64) {
        int i = i0 + lane;
        bool act = i < (int)cn;
        unsigned long long key = act ? cand[r][i] : 0ull;
        int bin = -1;
        if (act) bin = (int)((key2f((unsigned)(key >> 12)) - thg) * invg);
        bool pHi = act && bin > t, pBd = act && bin == t;
        unsigned long long mH = __ballot(pHi);
        unsigned offH = (unsigned)__popcll(mH & ltm);
        if (pHi && hiC + offH < K_) selKey[r][hiC + offH] = key;
        hiC += (unsigned)__popcll(mH);
        unsigned long long mB = __ballot(pBd);
        unsigned offB = (unsigned)__popcll(mB & ltm);
        if (pBd && bdC + offB < BCAP2) bndK[r][bdC + offB] = key;
        bdC += (unsigned)__popcll(mB);
      }
      if (bdC <= (unsigned)BCAP2) {
        if (lane < (int)bdC) {
          unsigned long long ki = bndK[r][lane];
          int rank = 0;
          for (int j = 0; j < (int)bdC; ++j) rank += (bndK[r][j] > ki) ? 1 : 0;
          if ((unsigned)rank < need) selKey[r][chi + rank] = ki;
        }
        fin = true;
      }
    }

    if (!fin) {
      // slow path (rare): operate on contiguous full-band superset [wlo, whi)
      float th = thg;
      float inv = invg;
      int wlo = ls[rlo * PB_], whi = ls[(rhi + 1) * PB_];

      if (cn >= (unsigned)K_) {
        // overflow case: rebuild hist over the band superset at the base threshold
        hist[r][lane] = 0u;
        cn = 0;
        for (int base = wlo; base < whi; base += 64) {
          int pos = base + lane;
          bool act = pos < whi;
          float c = -2.f;
          if (act) {
            float4 v = sl[pos];
            c = clamp1(v.x*p.x + v.y*p.y + v.z*p.z);
          }
          bool pr = c > th;
          if (pr) atomicAdd(&hist[r][(int)((c - th) * inv)], 1u);
          cn += (unsigned)__popcll(__ballot(pr));
        }
      }

      int tries = 0;
      while (cn < K_ && tries < 3) {
        th = 1.f - 1.6f*(1.f - th); ++tries;
        inv = 63.999f / (1.000001f - th);
        float al = acosf(clamp1(th));
        int blo = tband(thp - al - MG_), bhi = tband(thp + al + MG_);
        wlo = ls[blo * PB_]; whi = ls[(bhi + 1) * PB_];
        hist[r][lane] = 0u;
        cn = 0;
        for (int base = wlo; base < whi; base += 64) {
          int pos = base + lane;
          bool act = pos < whi;
          float c = -2.f;
          if (act) {
            float4 v = sl[pos];
            c = clamp1(v.x*p.x + v.y*p.y + v.z*p.z);
          }
          bool pr = c > th;
          if (pr) atomicAdd(&hist[r][(int)((c - th) * inv)], 1u);
          cn += (unsigned)__popcll(__ballot(pr));
        }
      }

      bool fin2 = false;
      if (cn >= K_) {
        unsigned g = hist[r][lane], s = g;
        #pragma unroll
        for (int off = 1; off < 64; off <<= 1) {
          unsigned t2 = (unsigned)__shfl_down((int)s, off);
          s += (lane + off < 64) ? t2 : 0u;
        }
        unsigned snext = s - g;
        unsigned packed = (s >= K_ && snext < K_) ? (((unsigned)(lane+1) << 16) | snext) : 0u;
        #pragma unroll
        for (int off = 32; off; off >>= 1) {
          unsigned o = (unsigned)__shfl_xor((int)packed, off);
          packed = packed > o ? packed : o;
        }
        const int t = (int)(packed >> 16) - 1;
        const unsigned chi = packed & 0xFFFFu;
        const unsigned need = K_ - chi;

        unsigned hiC = 0, bdC = 0;
        for (int base = wlo; base < whi; base += 64) {
          int pos = base + lane;
          bool act = pos < whi;
          float c = -2.f;
          if (act) {
            float4 v = sl[pos];
            c = clamp1(v.x*p.x + v.y*p.y + v.z*p.z);
          }
          int bin = (act && c > th) ? (int)((c - th) * inv) : -1;
          bool pHi = bin > t;
          bool pBd = bin == t;
          unsigned long long mH = __ballot(pHi);
          unsigned offH = (unsigned)__popcll(mH & ltm);
          if (pHi && hiC + offH < K_) selKey[r][hiC + offH] = spack(c, pos);
          hiC += (unsigned)__popcll(mH);
          unsigned long long mB = __ballot(pBd);
          unsigned offB = (unsigned)__popcll(mB & ltm);
          if (pBd && bdC + offB < BCAP2) bndK[r][bdC + offB] = spack(c, pos);
          bdC += (unsigned)__popcll(mB);
        }
        if (bdC <= (unsigned)BCAP2) {
          if (lane < (int)bdC) {
            unsigned long long ki = bndK[r][lane];
            int rank = 0;
            for (int j = 0; j < (int)bdC; ++j) rank += (bndK[r][j] > ki) ? 1 : 0;
            if ((unsigned)rank < need) selKey[r][chi + rank] = ki;
          }
          fin2 = true;
        }
      }

      if (!fin2) {
        // ultimate fallback: exact top-K over the sorted array (pos-keys)
        unsigned long long prev = ~0ull;
        for (int rd = 0; rd < K_; ++rd) {
          unsigned long long best = 0ull;
          for (int i = 0; i < 64; ++i) {
            int pos = lane + 64*i;
            float4 v = sl[pos];
            float c = clamp1(v.x*p.x + v.y*p.y + v.z*p.z);
            unsigned long long k = spack(c, pos);
            if (k < prev && k > best) best = k;
          }
          #pragma unroll
          for (int off = 1; off < 64; off <<= 1) {
            unsigned long long o = shflxor64(best, off);
            best = o > best ? o : best;
          }
          if (lane == 0) selKey[r][rd] = best;
          prev = best;
        }
      }
    }

    // attention MLP + softmax + weighted pool (decode pos; feature from slos.w)
    {
      unsigned long long key = selKey[r][lane];
      int pos = 4095 - (int)(key & 0xFFFull);
      float c = key2f((unsigned)(key >> 12));
      float xg = sl[pos].w;
      float d  = acosf(clamp1(c));
      float acc = ab2[0];
      for (int s2 = 0; s2 < SH_; ++s2)
        acc += fmaxf(xg*aw1[s2] + d*aw1[SH_+s2] + ab1[s2], 0.f) * aw2[s2];
      float mx = acc;
      #pragma unroll
      for (int off = 32; off; off >>= 1) mx = fmaxf(mx, __shfl_xor(mx, off));
      float e = expf(acc - mx);
      float se = e, sxe = e * xg;
      #pragma unroll
      for (int off = 32; off; off >>= 1) { se += __shfl_xor(se, off); sxe += __shfl_xor(sxe, off); }
      if (lane == 0) pooled[b*M_ + m] = sxe / se;
    }
  }
}

// ---------------- knn vK (coarse 2-D window, pos-keys; decode via sjdx at write) -------------
__global__ __launch_bounds__(512) void knn_vK(
    const float* __restrict__ pix,
    const float4* __restrict__ spix, const int* __restrict__ sjdx,
    const int* __restrict__ pstart,
    const float* __restrict__ kthrG, int* __restrict__ nbr)
{
  __shared__ unsigned long long cKey[16][KCAP];

  const int tid = threadIdx.x, wv = tid >> 6, lane = tid & 63;
  const int lr0 = wv*2;
  const int srow0 = blockIdx.x*16 + lr0, srow1 = srow0 + 1;
  const int i0 = sjdx[srow0], i1 = sjdx[srow1];
  const float4 p0 = spix[srow0], p1 = spix[srow1];
  const float thp0 = pix[2*i0], thp1 = pix[2*i1];
  const float php0 = pix[2*i0+1], php1 = pix[2*i1+1];
  const int g0 = thbkt(thp0), g1 = thbkt(thp1);
  const float t0 = fminf(kthrG[g0], kthrG[g0+1]);
  const float t1 = fminf(kthrG[g1], kthrG[g1+1]);
  const unsigned long long ltm = (1ull << lane) - 1ull;

  unsigned cnt0 = 0, cnt1 = 0;
  {
    float al0 = acosf(clamp1((t0 + 1.00002f)*0.5f));
    float al1 = acosf(clamp1((t1 + 1.00002f)*0.5f));
    int rlo = tband(fminf(thp0 - al0, thp1 - al1) - MG_);
    int rhi = tband(fmaxf(thp0 + al0, thp1 + al1) + MG_);
    int pbl, nb;
    phi_window(thp0, php0, al0, thp1, php1, al1, pbl, nb);

    auto doChunk = [&](int base, int e) {
      int pos = base + lane;
      bool act = pos < e;
      float s0 = -1e30f, s1 = -1e30f;
      if (act) {
        float4 v = spix[pos];
        s0 = 2.f*(p0.x*v.x + p0.y*v.y + p0.z*v.z) - v.w;
        s1 = 2.f*(p1.x*v.x + p1.y*v.y + p1.z*v.z) - v.w;
      }
      bool pr0 = act && (pos != srow0) && (s0 > t0);
      bool pr1 = act && (pos != srow1) && (s1 > t1);
      unsigned long long mk0 = __ballot(pr0);
      if (mk0) {
        unsigned off = (unsigned)__popcll(mk0 & ltm);
        if (pr0 && cnt0 + off < KCAP) cKey[lr0][cnt0 + off] = kpack(s0, pos);
        cnt0 += (unsigned)__popcll(mk0);
      }
      unsigned long long mk1 = __ballot(pr1);
      if (mk1) {
        unsigned off = (unsigned)__popcll(mk1 & ltm);
        if (pr1 && cnt1 + off < KCAP) cKey[lr0+1][cnt1 + off] = kpack(s1, pos);
        cnt1 += (unsigned)__popcll(mk1);
      }
    };
    for (int band = rlo; band <= rhi; ++band) {
      const int rb = band * PB_;
      if (pbl + nb <= PB_) {
        int s = pstart[rb + pbl], e = pstart[rb + pbl + nb];
        for (int base = s; base < e; base += 64) doChunk(base, e);
      } else {
        int s1 = pstart[rb + pbl], e1 = pstart[rb + PB_];
        for (int base = s1; base < e1; base += 64) doChunk(base, e1);
        int s2 = pstart[rb], e2 = pstart[rb + pbl + nb - PB_];
        for (int base = s2; base < e2; base += 64) doChunk(base, e2);
      }
    }
  }

  for (int rr = 0; rr < 2; ++rr) {
    const int lr = lr0 + rr;
    const int i  = (rr == 0) ? i0 : i1;
    const int srow = (rr == 0) ? srow0 : srow1;
    const float4 pi = (rr == 0) ? p0 : p1;
    const float thp = (rr == 0) ? thp0 : thp1;
    float th = (rr == 0) ? t0 : t1;
    unsigned cn = (rr == 0) ? cnt0 : cnt1;

    int tries = 0;
    while (cn < (unsigned)GK_ && tries < 3) {
      th = 1.6f*th - 0.6f; ++tries;
      float al = acosf(clamp1((th + 1.00002f)*0.5f));
      int blo = tband(thp - al - MG_), bhi = tband(thp + al + MG_);
      int jlo = pstart[blo * PB_], jhi = pstart[(bhi + 1) * PB_];
      cn = 0;
      for (int base = jlo; base < jhi; base += 64) {
        int pos = base + lane;
        bool act = pos < jhi;
        float s = -1e30f;
        if (act) {
          float4 v = spix[pos];
          s = 2.f*(pi.x*v.x + pi.y*v.y + pi.z*v.z) - v.w;
        }
        bool pr = act && (pos != srow) && (s > th);
        unsigned long long mk = __ballot(pr);
        if (mk) {
          unsigned off = (unsigned)__popcll(mk & ltm);
          if (pr && cn + off < KCAP) cKey[lr][cn + off] = kpack(s, pos);
          cn += (unsigned)__popcll(mk);
        }
      }
    }

    if (cn >= (unsigned)GK_ && cn <= (unsigned)KCAP) {
      unsigned long long pk[2];
      #pragma unroll
      for (int t2 = 0; t2 < 2; ++t2) {
        int idx = lane + 64*t2;
        pk[t2] = (idx < (int)cn) ? cKey[lr][idx] : 0ull;
      }
      for (int round = 0; round < GK_; ++round) {
        unsigned long long loc = pk[0]; int lt = 0;
        if (pk[1] > loc) { loc = pk[1]; lt = 1; }
        unsigned long long best = loc;
        #pragma unroll
        for (int off = 1; off < 64; off <<= 1) {
          unsigned long long o = shflxor64(best, off);
          best = o > best ? o : best;
        }
        if (loc == best) pk[lt] = 0ull;
        if (lane == round) nbr[i*GK_ + round] = sjdx[16383 - (int)(best & 16383ull)];
      }
    } else {
      unsigned long long prev = ~0ull;
      for (int rd = 0; rd < GK_; ++rd) {
        unsigned long long best = 0ull;
        for (int pos = lane; pos < M_; pos += 64) {
          float4 v = spix[pos];
          float s = 2.f*(pi.x*v.x + pi.y*v.y + pi.z*v.z) - v.w;
          if (pos != srow) {
            unsigned long long k = kpack(s, pos);
            if (k < prev && k > best) best = k;
          }
        }
        #pragma unroll
        for (int off = 1; off < 64; off <<= 1) {
          unsigned long long o = shflxor64(best, off);
          best = o > best ? o : best;
        }
        if (lane == rd) nbr[i*GK_ + rd] = sjdx[16383 - (int)(best & 16383ull)];
        prev = best;
      }
    }
  }
}

// ---------------- GNN layer 1 fused with proj (readlane matmul) ----------------
__global__ __launch_bounds__(256) void gnn1f_vK(
    const float* __restrict__ pooled, float* __restrict__ hout, const int* __restrict__ nbr,
    const float* __restrict__ pw, const float* __restrict__ pb,
    const float* __restrict__ relw, const float* __restrict__ relb,
    const float* __restrict__ rootw)
{
  __shared__ float wrel[H_*H_], wroot[H_*H_];
  const int tid = threadIdx.x;
  #pragma unroll
  for (int q = 0; q < 16; ++q) {
    int idx = tid + 256*q;
    wrel[idx]  = relw[idx];
    wroot[idx] = rootw[idx];
  }
  __syncthreads();

  const int lane = tid & 63;
  const int wave = tid >> 6;
  const int b = blockIdx.y;
  const int m0 = blockIdx.x * 16 + wave * 4;
  const float* pldb = pooled + (size_t)b * M_;
  const float pwl = pw[lane], pbl = pb[lane], rbl = relb[lane];

  float h[4], agg[4], acc[4];
  #pragma unroll
  for (int t = 0; t < 4; ++t) {
    int m = m0 + t;
    float ps = pldb[m];
    h[t] = fmaxf(ps*pwl + pbl, 0.f);
    float a = 0.f;
    #pragma unroll
    for (int k = 0; k < GK_; ++k) {
      int nb = nbr[m*GK_ + k];
      nb = nb < 0 ? 0 : (nb >= M_ ? M_-1 : nb);
      float pn = pldb[nb];
      a += fmaxf(pn*pwl + pbl, 0.f);
    }
    agg[t] = a;
    acc[t] = rbl;
  }
  #pragma unroll
  for (int c = 0; c < H_; ++c) {
    float wr = wrel[c*H_ + lane], wo = wroot[c*H_ + lane];
    #pragma unroll
    for (int t = 0; t < 4; ++t)
      acc[t] += rdlane(agg[t], c) * wr + rdlane(h[t], c) * wo;
  }
  #pragma unroll
  for (int t = 0; t < 4; ++t)
    hout[((size_t)b*M_ + m0 + t)*H_ + lane] = fmaxf(acc[t], 0.f);
}

// ---------------- GNN layer (generic, readlane matmul) ----------------
__global__ __launch_bounds__(256) void gnn_vK(
    const float* __restrict__ hin, float* __restrict__ hout, const int* __restrict__ nbr,
    const float* __restrict__ relw, const float* __restrict__ relb,
    const float* __restrict__ rootw)
{
  __shared__ float wrel[H_*H_], wroot[H_*H_];
  const int tid = threadIdx.x;
  #pragma unroll
  for (int q = 0; q < 16; ++q) {
    int idx = tid + 256*q;
    wrel[idx]  = relw[idx];
    wroot[idx] = rootw[idx];
  }
  __syncthreads();

  const int lane = tid & 63;
  const int wave = tid >> 6;
  const int b = blockIdx.y;
  const int m0 = blockIdx.x * 16 + wave * 4;
  const float* hb = hin + (size_t)b * M_ * H_;
  const float rbl = relb[lane];

  float h[4], agg[4], acc[4];
  #pragma unroll
  for (int t = 0; t < 4; ++t) {
    int m = m0 + t;
    h[t] = hb[m*H_ + lane];
    float a = 0.f;
    #pragma unroll
    for (int k = 0; k < GK_; ++k) {
      int nb = nbr[m*GK_ + k];
      nb = nb < 0 ? 0 : (nb >= M_ ? M_-1 : nb);
      a += hb[nb*H_ + lane];
    }
    agg[t] = a;
    acc[t] = rbl;
  }
  #pragma unroll
  for (int c = 0; c < H_; ++c) {
    float wr = wrel[c*H_ + lane], wo = wroot[c*H_ + lane];
    #pragma unroll
    for (int t = 0; t < 4; ++t)
      acc[t] += rdlane(agg[t], c) * wr + rdlane(h[t], c) * wo;
  }
  #pragma unroll
  for (int t = 0; t < 4; ++t)
    hout[((size_t)b*M_ + m0 + t)*H_ + lane] = fmaxf(acc[t], 0.f);
}

// ---------------- GNN layer 3 + fused global-mean reduce ----------------
__global__ __launch_bounds__(256) void gnn3r_vK(
    const float* __restrict__ hin, float* __restrict__ gf, const int* __restrict__ nbr,
    const float* __restrict__ relw, const float* __restrict__ relb,
    const float* __restrict__ rootw)
{
  __shared__ float wrel[H_*H_], wroot[H_*H_];
  __shared__ float gacc[H_];
  const int tid = threadIdx.x;
  #pragma unroll
  for (int q = 0; q < 16; ++q) {
    int idx = tid + 256*q;
    wrel[idx]  = relw[idx];
    wroot[idx] = rootw[idx];
  }
  if (tid < H_) gacc[tid] = 0.f;
  __syncthreads();

  const int lane = tid & 63;
  const int wave = tid >> 6;
  const int b = blockIdx.y;
  const int m0 = blockIdx.x * 16 + wave * 4;
  const float* hb = hin + (size_t)b * M_ * H_;
  const float rbl = relb[lane];

  float h[4], agg[4], acc[4];
  #pragma unroll
  for (int t = 0; t < 4; ++t) {
    int m = m0 + t;
    h[t] = hb[m*H_ + lane];
    float a = 0.f;
    #pragma unroll
    for (int k = 0; k < GK_; ++k) {
      int nb = nbr[m*GK_ + k];
      nb = nb < 0 ? 0 : (nb >= M_ ? M_-1 : nb);
      a += hb[nb*H_ + lane];
    }
    agg[t] = a;
    acc[t] = rbl;
  }
  #pragma unroll
  for (int c = 0; c < H_; ++c) {
    float wr = wrel[c*H_ + lane], wo = wroot[c*H_ + lane];
    #pragma unroll
    for (int t = 0; t < 4; ++t)
      acc[t] += rdlane(agg[t], c) * wr + rdlane(h[t], c) * wo;
  }
  float ps = fmaxf(acc[0], 0.f) + fmaxf(acc[1], 0.f) + fmaxf(acc[2], 0.f) + fmaxf(acc[3], 0.f);
  atomicAdd(&gacc[lane], ps);
  __syncthreads();
  if (tid < H_) atomicAdd(&gf[b*H_ + tid], gacc[tid]);
}

// ---------------- head ----------------
__global__ __launch_bounds__(256) void head_vK(
    const float* __restrict__ gf, const float* __restrict__ w1,
    const float* __restrict__ b1, const float* __restrict__ w2,
    const float* __restrict__ b2, float* __restrict__ out)
{
  __shared__ float gfm[B_][H_], hid[B_][H_];
  const int tid = threadIdx.x;
  if (tid < B_*H_) gfm[tid >> 6][tid & 63] = gf[tid] * (1.f / (float)M_);
  __syncthreads();
  if (tid < B_*H_) {
    int b = tid >> 6, j = tid & 63;
    float acc = b1[j];
    for (int c = 0; c < H_; ++c) acc += gfm[b][c] * w1[c*H_ + j];
    hid[b][j] = fmaxf(acc, 0.f);
  }
  __syncthreads();
  for (int t = tid; t < B_*NC_; t += 256) {
    int b = t / NC_, o = t - b*NC_;
    float acc = b2[o];
    for (int j = 0; j < H_; ++j) acc += hid[b][j] * w2[j*NC_ + o];
    out[t] = acc;
  }
}

extern "C" void kernel_launch(void* const* d_in, const int* in_sizes, int n_in,
                              void* d_out, int out_size, void* d_ws, size_t ws_size,
                              hipStream_t stream)
{
  float* out = (float*)d_out;

  const size_t need = (size_t)M_*16 + (size_t)B_*N_*16 + (size_t)B_*M_*4
                    + (size_t)M_*GK_*4 + 2*(size_t)B_*M_*H_*4 + (size_t)B_*H_*4;
  bool ok_ws = ws_size >= need;
  bool ok_in = (n_in == 15) && (out_size == B_*NC_)
            && in_sizes[0] == B_*3*N_ && in_sizes[1] == M_*2
            && in_sizes[2] == 2*SH_ && in_sizes[5] == 1
            && in_sizes[8] == 3*H_*H_ && in_sizes[13] == H_*NC_;
  if (!ok_ws || !ok_in) {
    sentinel_vK<<<(out_size + 255)/256, 256, 0, stream>>>(out, out_size, ok_in ? 42.f : 43.f);
    return;
  }

  const float* xxx    = (const float*)d_in[0];
  const float* pix    = (const float*)d_in[1];
  const float* att_w1 = (const float*)d_in[2];
  const float* att_b1 = (const float*)d_in[3];
  const float* att_w2 = (const float*)d_in[4];
  const float* att_b2 = (const float*)d_in[5];
  const float* proj_w = (const float*)d_in[6];
  const float* proj_b = (const float*)d_in[7];
  const float* rel_w  = (const float*)d_in[8];
  const float* rel_b  = (const float*)d_in[9];
  const float* root_w = (const float*)d_in[10];
  const float* out_w1 = (const float*)d_in[11];
  const float* out_b1 = (const float*)d_in[12];
  const float* out_w2 = (const float*)d_in[13];
  const float* out_b2 = (const float*)d_in[14];

  char* w = (char*)d_ws;
  float4* r_pix = (float4*)w;  w += (size_t)M_ * 16;
  float4* r_los = (float4*)w;  w += (size_t)B_ * N_ * 16;
  float*  pooled = (float*)w;  w += (size_t)B_ * M_ * 4;
  int*    nbr = (int*)w;       w += (size_t)M_ * GK_ * 4;
  float*  h0 = (float*)w;      w += (size_t)B_ * M_ * H_ * 4;
  float*  h1 = (float*)w;      w += (size_t)B_ * M_ * H_ * 4;
  float*  gf = (float*)w;      w += (size_t)B_ * H_ * 4;

  // sort/threshold scratch aliases h0 (dead until gnn layer 2 writes it)
  float*  kthrG = h0;                                  // 257 grid thresholds (knn)
  float*  cthrG = h0 + 512;                            // 257 grid thresholds (sampler)
  float4* spix = (float4*)(h0 + 2*M_);                 // M float4
  int*    sjdx = (int*)(h0 + 6*M_);                    // M
  float4* slos = (float4*)(h0 + 7*M_);                 // B*N float4
  unsigned* cnt = (unsigned*)(h0 + 7*M_ + 5*B_*N_);    // 768
  int*    pstart = (int*)(cnt + 768);                  // 257
  int*    lstart = pstart + 257;                       // 2*257
  unsigned* pcur = (unsigned*)(lstart + 514);          // 256
  unsigned* lcur = pcur + 256;                         // 512

  hipMemsetAsync(cnt, 0, 768*sizeof(unsigned), stream);
  prep_vK<<<GRIDB_ + PREPB_, 256, 0, stream>>>(xxx, pix, r_pix, r_los, gf, kthrG, cthrG, cnt);
  scan_vK<<<1, 256, 0, stream>>>(cnt, pstart, lstart, pcur, lcur);
  scatter_vK<<<(M_ + B_*N_ + 255)/256, 256, 0, stream>>>(xxx, pix, r_pix, r_los, pcur, lcur,
                                                         spix, sjdx, slos);
  sampler_vK<<<dim3(M_/16, B_), 512, 0, stream>>>(pix, spix, sjdx, slos, lstart,
                                                  cthrG, att_w1, att_b1, att_w2, att_b2, pooled);
  knn_vK<<<M_/16, 512, 0, stream>>>(pix, spix, sjdx, pstart, kthrG, nbr);
  gnn1f_vK<<<dim3(M_/16, B_), 256, 0, stream>>>(pooled, h1, nbr, proj_w, proj_b,
                                                rel_w + 0*H_*H_, rel_b + 0*H_, root_w + 0*H_*H_);
  gnn_vK<<<dim3(M_/16, B_), 256, 0, stream>>>(h1, h0, nbr, rel_w + 1*H_*H_, rel_b + 1*H_, root_w + 1*H_*H_);
  gnn3r_vK<<<dim3(M_/16, B_), 256, 0, stream>>>(h0, gf, nbr, rel_w + 2*H_*H_, rel_b + 2*H_, root_w + 2*H_*H_);
  head_vK<<<1, 256, 0, stream>>>(gf, out_w1, out_b1, out_w2, out_b2, out);
}

// Round 7
// 243.439 us; speedup vs baseline: 1.0811x; 1.0811x over previous
//
#include <hip/hip_runtime.h>
#include <hip/hip_bf16.h>

#define B_ 2
#define N_ 4096
#define M_ 12288
#define K_ 64
#define SH_ 32
#define H_ 64
#define GK_ 8
#define NC_ 200

#define KCAP 128       // knn candidate cap (E=40, +13 sigma)
#define BCAP2 48       // sampler boundary cap
#define SCAP 144       // sampler stored-candidate cap (E=96, +4.9 sigma; overflow -> slow path)
#define MG_ 0.01f      // theta-window safety margin (rad)
#define C256_ 81.48733086f   // 256/pi

static __device__ __forceinline__ unsigned f2key(float f) {
  unsigned b = __float_as_uint(f);
  return (b & 0x80000000u) ? ~b : (b | 0x80000000u);
}
static __device__ __forceinline__ float key2f(unsigned u) {
  unsigned b = (u & 0x80000000u) ? (u & 0x7fffffffu) : ~u;
  return __uint_as_float(b);
}
static __device__ __forceinline__ unsigned long long shflxor64(unsigned long long x, int m) {
  unsigned lo = (unsigned)x, hi = (unsigned)(x >> 32);
  lo = (unsigned)__shfl_xor((int)lo, m);
  hi = (unsigned)__shfl_xor((int)hi, m);
  return ((unsigned long long)hi << 32) | lo;
}
// keys carry SORTED positions (known from loop counter; no index load in scans)
static __device__ __forceinline__ unsigned long long kpack(float s, int pos) {
  return ((unsigned long long)f2key(s) << 14) | (unsigned)(16383 - pos);
}
static __device__ __forceinline__ unsigned long long spack(float c, int pos) {
  return ((unsigned long long)f2key(c) << 12) | (unsigned)(4095 - pos);
}
static __device__ __forceinline__ int thbkt(float th) {
  int b = (int)(th * C256_);
  return b < 0 ? 0 : (b > 255 ? 255 : b);
}
static __device__ __forceinline__ float clamp1(float x) { return fminf(1.f, fmaxf(-1.f, x)); }
static __device__ __forceinline__ float rdlane(float v, int c) {
  return __uint_as_float((unsigned)__builtin_amdgcn_readlane((int)__float_as_uint(v), c));
}

// ---------------- sentinel ----------------
__global__ __launch_bounds__(256) void sentinel_vL(float* out, int n, float val) {
  int t = blockIdx.x * 256 + threadIdx.x;
  if (t < n) out[t] = val;
}

// ---------------- prep + GRID thresholds (257-pt theta grid) + theta-band hist ----------------
#define GRIDB_ 129     // 129 blocks x 4 waves = 516 jobs >= 2*257
#define PREPN_ (M_ + B_*N_ + B_*H_)
#define PREPB_ ((PREPN_ + 255)/256)

__global__ __launch_bounds__(256) void prep_vL(
    const float* __restrict__ xxx, const float* __restrict__ pix,
    float4* __restrict__ r_pix, float4* __restrict__ r_los, float* __restrict__ gf,
    float* __restrict__ kthrG, float* __restrict__ cthrG, unsigned* __restrict__ cnt)
{
  const float PI = 3.14159265358979f;
  if ((int)blockIdx.x < GRIDB_) {
    int gid  = blockIdx.x*4 + (threadIdx.x >> 6);
    if (gid >= 514) return;
    int lane = threadIdx.x & 63;
    int tgt  = (gid >= 257) ? 1 : 0;
    int gp   = gid - tgt*257;
    float thp = (float)gp * (PI/256.f);
    float cp = cosf(thp), sp = fmaxf(sinf(thp), 1e-6f);
    float thq = ((float)lane + 0.5f) * (PI/64.f);
    float sq = sinf(thq), cq = cosf(thq);
    float rinv = 1.0f / (sq * sp);
    // E targets: sampler 96 of N, knn 40 of M (top-K invariant to threshold while count>=K;
    // retry ladder covers the ~5e-4 under-count tail)
    float At = tgt ? (2.f*PI*PI*96.f/(float)N_) : (2.f*PI*PI*40.f/(float)M_);
    float lo = 1e-3f, hi = 3.1414f;
    for (int it = 0; it < 12; ++it) {
      float al = 0.5f*(lo + hi);
      float ca = cosf(al);
      float arg = clamp1((ca - cq*cp) * rinv);
      float ax = fabsf(arg);
      float ac = sqrtf(fmaxf(0.f, 1.f - ax)) *
                 fmaf(ax, fmaf(ax, fmaf(ax, -0.0187293f, 0.0742610f), -0.2121144f), 1.5707288f);
      ac = (arg < 0.f) ? (PI - ac) : ac;
      float S = ac;
      #pragma unroll
      for (int off = 32; off; off >>= 1) S += __shfl_xor(S, off);
      float A = 2.f * S * (PI/64.f);
      if (A < At) lo = al; else hi = al;
    }
    if (lane == 0) {
      float chv = cosf(hi);
      if (tgt) cthrG[gp] = chv - 1e-5f;
      else     kthrG[gp] = 2.f*chv - 1.00002f;
    }
  } else {
    int tid = ((int)blockIdx.x - GRIDB_)*256 + threadIdx.x;
    if (tid < M_) {
      float th = pix[2*tid], ph = pix[2*tid+1];
      float st = sinf(th);
      float x = st*cosf(ph), y = st*sinf(ph), z = cosf(th);
      r_pix[tid] = make_float4(x, y, z, x*x + y*y + z*z);
      atomicAdd(&cnt[thbkt(th)], 1u);
    }
    int t2 = tid - M_;
    if (t2 >= 0 && t2 < B_*N_) {
      int b = t2 >> 12, n = t2 & (N_-1);
      const float* xb = xxx + b*3*N_;
      float th = xb[n], ph = xb[N_+n], ft = xb[2*N_+n];
      float st = sinf(th);
      r_los[t2] = make_float4(st*cosf(ph), st*sinf(ph), cosf(th), ft);
      atomicAdd(&cnt[256 + b*256 + thbkt(th)], 1u);
    }
    int t3 = tid - M_ - B_*N_;
    if (t3 >= 0 && t3 < B_*H_) gf[t3] = 0.0f;
  }
}

// ---------------- scan ----------------
__global__ __launch_bounds__(256) void scan_vL(
    const unsigned* __restrict__ cnt, int* __restrict__ pstart, int* __restrict__ lstart,
    unsigned* __restrict__ pcur, unsigned* __restrict__ lcur)
{
  __shared__ unsigned buf[256];
  const int t = threadIdx.x;
  for (int arr = 0; arr < 3; ++arr) {
    unsigned v = cnt[arr*256 + t];
    buf[t] = v;
    __syncthreads();
    for (int off = 1; off < 256; off <<= 1) {
      unsigned o = (t >= off) ? buf[t - off] : 0u;
      __syncthreads();
      buf[t] += o;
      __syncthreads();
    }
    unsigned incl = buf[t], excl = incl - v;
    if (arr == 0) {
      pstart[t] = (int)excl; if (t == 255) pstart[256] = (int)incl;
      pcur[t] = excl;
    } else {
      int b = arr - 1;
      lstart[b*257 + t] = (int)excl; if (t == 255) lstart[b*257 + 256] = (int)incl;
      lcur[b*256 + t] = excl;
    }
    __syncthreads();
  }
}

// ---------------- scatter (sldx not needed: sampler keys carry sorted pos) -------------
__global__ __launch_bounds__(256) void scatter_vL(
    const float* __restrict__ xxx, const float* __restrict__ pix,
    const float4* __restrict__ r_pix, const float4* __restrict__ r_los,
    unsigned* __restrict__ pcur, unsigned* __restrict__ lcur,
    float4* __restrict__ spix, int* __restrict__ sjdx,
    float4* __restrict__ slos)
{
  int tid = blockIdx.x * 256 + threadIdx.x;
  if (tid < M_) {
    int bkt = thbkt(pix[2*tid]);
    unsigned pos = atomicAdd(&pcur[bkt], 1u);
    spix[pos] = r_pix[tid];
    sjdx[pos] = tid;
  } else {
    int t2 = tid - M_;
    if (t2 < B_*N_) {
      int b = t2 >> 12, n = t2 & (N_-1);
      int bkt = thbkt(xxx[b*3*N_ + n]);
      unsigned pos = atomicAdd(&lcur[b*256 + bkt], 1u);
      slos[b*N_ + pos] = r_los[t2];
    }
  }
}

// ---------------- FUSED sampler+knn (vJ bodies verbatim; blockIdx.y==B_ -> knn path) ----------
// Neither path uses __syncthreads (LDS is wave-private), so the block-level branch is safe.
// LDS: 36864 B union (sampler: cand+selKey+bndK+hist; knn: cKey) -> 4 blocks/CU either way.
__global__ __launch_bounds__(512) void sampknn_vL(
    const float* __restrict__ pix,
    const float4* __restrict__ spix, const int* __restrict__ sjdx,
    const float4* __restrict__ slos,
    const int* __restrict__ lstart, const int* __restrict__ pstart,
    const float* __restrict__ cthrG, const float* __restrict__ kthrG,
    const float* __restrict__ aw1, const float* __restrict__ ab1,
    const float* __restrict__ aw2, const float* __restrict__ ab2,
    float* __restrict__ pooled, int* __restrict__ nbr)
{
  __shared__ unsigned long long smem[16*SCAP + 16*K_ + 16*BCAP2 + 16*32];  // 36864 B

  const int tid = threadIdx.x, wv = tid >> 6, lane = tid & 63;
  const unsigned long long ltm = (1ull << lane) - 1ull;

  if ((int)blockIdx.y < B_) {
    // ================= sampler path (vJ verbatim) =================
    unsigned long long (*cand)[SCAP]  = (unsigned long long(*)[SCAP])smem;
    unsigned long long (*selKey)[K_]  = (unsigned long long(*)[K_])(smem + 16*SCAP);
    unsigned long long (*bndK)[BCAP2] = (unsigned long long(*)[BCAP2])(smem + 16*SCAP + 16*K_);
    unsigned (*hist)[64] = (unsigned(*)[64])(smem + 16*SCAP + 16*K_ + 16*BCAP2);

    const int b  = blockIdx.y;
    const int srow0 = blockIdx.x*16 + wv*2, srow1 = srow0 + 1;
    const int r0 = wv*2, r1 = r0 + 1;
    const int m0 = sjdx[srow0], m1 = sjdx[srow1];
    const float4 p0 = spix[srow0], p1 = spix[srow1];
    const float thp0 = pix[2*m0], thp1 = pix[2*m1];
    const int g0 = thbkt(thp0), g1 = thbkt(thp1);
    const float th0 = fminf(cthrG[g0], cthrG[g0+1]);
    const float th1 = fminf(cthrG[g1], cthrG[g1+1]);
    const float inv0 = 63.999f / (1.000001f - th0);
    const float inv1 = 63.999f / (1.000001f - th1);
    const float4* sl = slos + b * N_;
    const int* ls = lstart + b * 257;

    // union window bounds
    int jlo, jhi;
    {
      float al0 = acosf(clamp1(th0)), al1 = acosf(clamp1(th1));
      int blo = thbkt(fminf(thp0 - al0, thp1 - al1) - MG_);
      int bhi = thbkt(fmaxf(thp0 + al0, thp1 + al1) + MG_);
      jlo = ls[blo]; jhi = ls[bhi + 1];
    }

    // single pass: dot, predicate, compact candidates of both rows into LDS (pos-keys)
    unsigned cnt0 = 0, cnt1 = 0;
    for (int base = jlo; base < jhi; base += 64) {
      int pos = base + lane;
      bool act = pos < jhi;
      float c0 = -2.f, c1 = -2.f;
      if (act) {
        float4 v = sl[pos];
        c0 = clamp1(v.x*p0.x + v.y*p0.y + v.z*p0.z);
        c1 = clamp1(v.x*p1.x + v.y*p1.y + v.z*p1.z);
      }
      bool pr0 = c0 > th0, pr1 = c1 > th1;
      unsigned long long mk0 = __ballot(pr0);
      if (mk0) {
        unsigned off = (unsigned)__popcll(mk0 & ltm);
        if (pr0 && cnt0 + off < SCAP) cand[r0][cnt0 + off] = spack(c0, pos);
        cnt0 += (unsigned)__popcll(mk0);
      }
      unsigned long long mk1 = __ballot(pr1);
      if (mk1) {
        unsigned off = (unsigned)__popcll(mk1 & ltm);
        if (pr1 && cnt1 + off < SCAP) cand[r1][cnt1 + off] = spack(c1, pos);
        cnt1 += (unsigned)__popcll(mk1);
      }
    }

    for (int rr = 0; rr < 2; ++rr) {
      const int r = (rr == 0) ? r0 : r1;
      const int m = (rr == 0) ? m0 : m1;
      const float4 p = (rr == 0) ? p0 : p1;
      const float thp = (rr == 0) ? thp0 : thp1;
      const float thg = (rr == 0) ? th0 : th1;
      const float invg = (rr == 0) ? inv0 : inv1;
      unsigned cn = (rr == 0) ? cnt0 : cnt1;
      bool fin = false;

      // fast path: all candidates captured in LDS
      if (cn >= (unsigned)K_ && cn <= (unsigned)SCAP) {
        hist[r][lane] = 0u;
        for (int i = lane; i < (int)cn; i += 64) {
          float c = key2f((unsigned)(cand[r][i] >> 12));
          atomicAdd(&hist[r][(int)((c - thg) * invg)], 1u);
        }
        unsigned g = hist[r][lane], s = g;
        #pragma unroll
        for (int off = 1; off < 64; off <<= 1) {
          unsigned t2 = (unsigned)__shfl_down((int)s, off);
          s += (lane + off < 64) ? t2 : 0u;
        }
        unsigned snext = s - g;
        unsigned packed = (s >= K_ && snext < K_) ? (((unsigned)(lane+1) << 16) | snext) : 0u;
        #pragma unroll
        for (int off = 32; off; off >>= 1) {
          unsigned o = (unsigned)__shfl_xor((int)packed, off);
          packed = packed > o ? packed : o;
        }
        const int t = (int)(packed >> 16) - 1;
        const unsigned chi = packed & 0xFFFFu;
        const unsigned need = K_ - chi;

        unsigned hiC = 0, bdC = 0;
        for (int i0 = 0; i0 < (int)cn; i0 += 64) {
          int i = i0 + lane;
          bool act = i < (int)cn;
          unsigned long long key = act ? cand[r][i] : 0ull;
          int bin = -1;
          if (act) bin = (int)((key2f((unsigned)(key >> 12)) - thg) * invg);
          bool pHi = act && bin > t, pBd = act && bin == t;
          unsigned long long mH = __ballot(pHi);
          unsigned offH = (unsigned)__popcll(mH & ltm);
          if (pHi && hiC + offH < K_) selKey[r][hiC + offH] = key;
          hiC += (unsigned)__popcll(mH);
          unsigned long long mB = __ballot(pBd);
          unsigned offB = (unsigned)__popcll(mB & ltm);
          if (pBd && bdC + offB < BCAP2) bndK[r][bdC + offB] = key;
          bdC += (unsigned)__popcll(mB);
        }
        if (bdC <= (unsigned)BCAP2) {
          if (lane < (int)bdC) {
            unsigned long long ki = bndK[r][lane];
            int rank = 0;
            for (int j = 0; j < (int)bdC; ++j) rank += (bndK[r][j] > ki) ? 1 : 0;
            if ((unsigned)rank < need) selKey[r][chi + rank] = ki;
          }
          fin = true;
        }
      }

      if (!fin) {
        // slow path (rare)
        float th = thg;
        float inv = invg;
        int wlo = jlo, whi = jhi;

        if (cn >= (unsigned)K_) {
          hist[r][lane] = 0u;
          cn = 0;
          for (int base = wlo; base < whi; base += 64) {
            int pos = base + lane;
            bool act = pos < whi;
            float c = -2.f;
            if (act) {
              float4 v = sl[pos];
              c = clamp1(v.x*p.x + v.y*p.y + v.z*p.z);
            }
            bool pr = c > th;
            if (pr) atomicAdd(&hist[r][(int)((c - th) * inv)], 1u);
            cn += (unsigned)__popcll(__ballot(pr));
          }
        }

        int tries = 0;
        while (cn < K_ && tries < 3) {
          th = 1.f - 1.6f*(1.f - th); ++tries;
          inv = 63.999f / (1.000001f - th);
          float al = acosf(clamp1(th));
          int blo = thbkt(thp - al - MG_), bhi = thbkt(thp + al + MG_);
          wlo = ls[blo]; whi = ls[bhi + 1];
          hist[r][lane] = 0u;
          cn = 0;
          for (int base = wlo; base < whi; base += 64) {
            int pos = base + lane;
            bool act = pos < whi;
            float c = -2.f;
            if (act) {
              float4 v = sl[pos];
              c = clamp1(v.x*p.x + v.y*p.y + v.z*p.z);
            }
            bool pr = c > th;
            if (pr) atomicAdd(&hist[r][(int)((c - th) * inv)], 1u);
            cn += (unsigned)__popcll(__ballot(pr));
          }
        }

        bool fin2 = false;
        if (cn >= K_) {
          unsigned g = hist[r][lane], s = g;
          #pragma unroll
          for (int off = 1; off < 64; off <<= 1) {
            unsigned t2 = (unsigned)__shfl_down((int)s, off);
            s += (lane + off < 64) ? t2 : 0u;
          }
          unsigned snext = s - g;
          unsigned packed = (s >= K_ && snext < K_) ? (((unsigned)(lane+1) << 16) | snext) : 0u;
          #pragma unroll
          for (int off = 32; off; off >>= 1) {
            unsigned o = (unsigned)__shfl_xor((int)packed, off);
            packed = packed > o ? packed : o;
          }
          const int t = (int)(packed >> 16) - 1;
          const unsigned chi = packed & 0xFFFFu;
          const unsigned need = K_ - chi;

          unsigned hiC = 0, bdC = 0;
          for (int base = wlo; base < whi; base += 64) {
            int pos = base + lane;
            bool act = pos < whi;
            float c = -2.f;
            if (act) {
              float4 v = sl[pos];
              c = clamp1(v.x*p.x + v.y*p.y + v.z*p.z);
            }
            int bin = (act && c > th) ? (int)((c - th) * inv) : -1;
            bool pHi = bin > t;
            bool pBd = bin == t;
            unsigned long long mH = __ballot(pHi);
            unsigned offH = (unsigned)__popcll(mH & ltm);
            if (pHi && hiC + offH < K_) selKey[r][hiC + offH] = spack(c, pos);
            hiC += (unsigned)__popcll(mH);
            unsigned long long mB = __ballot(pBd);
            unsigned offB = (unsigned)__popcll(mB & ltm);
            if (pBd && bdC + offB < BCAP2) bndK[r][bdC + offB] = spack(c, pos);
            bdC += (unsigned)__popcll(mB);
          }
          if (bdC <= (unsigned)BCAP2) {
            if (lane < (int)bdC) {
              unsigned long long ki = bndK[r][lane];
              int rank = 0;
              for (int j = 0; j < (int)bdC; ++j) rank += (bndK[r][j] > ki) ? 1 : 0;
              if ((unsigned)rank < need) selKey[r][chi + rank] = ki;
            }
            fin2 = true;
          }
        }

        if (!fin2) {
          // ultimate fallback: exact top-K over the sorted array (pos-keys)
          unsigned long long prev = ~0ull;
          for (int rd = 0; rd < K_; ++rd) {
            unsigned long long best = 0ull;
            for (int i = 0; i < 64; ++i) {
              int pos = lane + 64*i;
              float4 v = sl[pos];
              float c = clamp1(v.x*p.x + v.y*p.y + v.z*p.z);
              unsigned long long k = spack(c, pos);
              if (k < prev && k > best) best = k;
            }
            #pragma unroll
            for (int off = 1; off < 64; off <<= 1) {
              unsigned long long o = shflxor64(best, off);
              best = o > best ? o : best;
            }
            if (lane == 0) selKey[r][rd] = best;
            prev = best;
          }
        }
      }

      // attention MLP + softmax + weighted pool
      {
        unsigned long long key = selKey[r][lane];
        int pos = 4095 - (int)(key & 0xFFFull);
        float c = key2f((unsigned)(key >> 12));
        float xg = sl[pos].w;
        float d  = acosf(clamp1(c));
        float acc = ab2[0];
        for (int s2 = 0; s2 < SH_; ++s2)
          acc += fmaxf(xg*aw1[s2] + d*aw1[SH_+s2] + ab1[s2], 0.f) * aw2[s2];
        float mx = acc;
        #pragma unroll
        for (int off = 32; off; off >>= 1) mx = fmaxf(mx, __shfl_xor(mx, off));
        float e = expf(acc - mx);
        float se = e, sxe = e * xg;
        #pragma unroll
        for (int off = 32; off; off >>= 1) { se += __shfl_xor(se, off); sxe += __shfl_xor(sxe, off); }
        if (lane == 0) pooled[b*M_ + m] = sxe / se;
      }
    }
  } else {
    // ================= knn path (vJ verbatim) =================
    unsigned long long (*cKey)[KCAP] = (unsigned long long(*)[KCAP])smem;

    const int lr0 = wv*2;
    const int srow0 = blockIdx.x*16 + lr0, srow1 = srow0 + 1;
    const int i0 = sjdx[srow0], i1 = sjdx[srow1];
    const float4 p0 = spix[srow0], p1 = spix[srow1];
    const float thp0 = pix[2*i0], thp1 = pix[2*i1];
    const int g0 = thbkt(thp0), g1 = thbkt(thp1);
    const float t0 = fminf(kthrG[g0], kthrG[g0+1]);
    const float t1 = fminf(kthrG[g1], kthrG[g1+1]);

    unsigned cnt0 = 0, cnt1 = 0;
    {
      float al0 = acosf(clamp1((t0 + 1.00002f)*0.5f));
      float al1 = acosf(clamp1((t1 + 1.00002f)*0.5f));
      int blo = thbkt(fminf(thp0 - al0, thp1 - al1) - MG_);
      int bhi = thbkt(fmaxf(thp0 + al0, thp1 + al1) + MG_);
      int jlo = pstart[blo], jhi = pstart[bhi + 1];
      for (int base = jlo; base < jhi; base += 64) {
        int pos = base + lane;
        bool act = pos < jhi;
        float s0 = -1e30f, s1 = -1e30f;
        if (act) {
          float4 v = spix[pos];
          s0 = 2.f*(p0.x*v.x + p0.y*v.y + p0.z*v.z) - v.w;
          s1 = 2.f*(p1.x*v.x + p1.y*v.y + p1.z*v.z) - v.w;
        }
        bool pr0 = act && (pos != srow0) && (s0 > t0);
        bool pr1 = act && (pos != srow1) && (s1 > t1);
        unsigned long long mk0 = __ballot(pr0);
        if (mk0) {
          unsigned off = (unsigned)__popcll(mk0 & ltm);
          if (pr0 && cnt0 + off < KCAP) cKey[lr0][cnt0 + off] = kpack(s0, pos);
          cnt0 += (unsigned)__popcll(mk0);
        }
        unsigned long long mk1 = __ballot(pr1);
        if (mk1) {
          unsigned off = (unsigned)__popcll(mk1 & ltm);
          if (pr1 && cnt1 + off < KCAP) cKey[lr0+1][cnt1 + off] = kpack(s1, pos);
          cnt1 += (unsigned)__popcll(mk1);
        }
      }
    }

    for (int rr = 0; rr < 2; ++rr) {
      const int lr = lr0 + rr;
      const int i  = (rr == 0) ? i0 : i1;
      const int srow = (rr == 0) ? srow0 : srow1;
      const float4 pi = (rr == 0) ? p0 : p1;
      const float thp = (rr == 0) ? thp0 : thp1;
      float th = (rr == 0) ? t0 : t1;
      unsigned cn = (rr == 0) ? cnt0 : cnt1;

      int tries = 0;
      while (cn < (unsigned)GK_ && tries < 3) {
        th = 1.6f*th - 0.6f; ++tries;
        float al = acosf(clamp1((th + 1.00002f)*0.5f));
        int blo = thbkt(thp - al - MG_), bhi = thbkt(thp + al + MG_);
        int jlo = pstart[blo], jhi = pstart[bhi + 1];
        cn = 0;
        for (int base = jlo; base < jhi; base += 64) {
          int pos = base + lane;
          bool act = pos < jhi;
          float s = -1e30f;
          if (act) {
            float4 v = spix[pos];
            s = 2.f*(pi.x*v.x + pi.y*v.y + pi.z*v.z) - v.w;
          }
          bool pr = act && (pos != srow) && (s > th);
          unsigned long long mk = __ballot(pr);
          if (mk) {
            unsigned off = (unsigned)__popcll(mk & ltm);
            if (pr && cn + off < KCAP) cKey[lr][cn + off] = kpack(s, pos);
            cn += (unsigned)__popcll(mk);
          }
        }
      }

      if (cn >= (unsigned)GK_ && cn <= (unsigned)KCAP) {
        unsigned long long pk[2];
        #pragma unroll
        for (int t2 = 0; t2 < 2; ++t2) {
          int idx = lane + 64*t2;
          pk[t2] = (idx < (int)cn) ? cKey[lr][idx] : 0ull;
        }
        for (int round = 0; round < GK_; ++round) {
          unsigned long long loc = pk[0]; int lt = 0;
          if (pk[1] > loc) { loc = pk[1]; lt = 1; }
          unsigned long long best = loc;
          #pragma unroll
          for (int off = 1; off < 64; off <<= 1) {
            unsigned long long o = shflxor64(best, off);
            best = o > best ? o : best;
          }
          if (loc == best) pk[lt] = 0ull;
          if (lane == round) nbr[i*GK_ + round] = sjdx[16383 - (int)(best & 16383ull)];
        }
      } else {
        unsigned long long prev = ~0ull;
        for (int rd = 0; rd < GK_; ++rd) {
          unsigned long long best = 0ull;
          for (int pos = lane; pos < M_; pos += 64) {
            float4 v = spix[pos];
            float s = 2.f*(pi.x*v.x + pi.y*v.y + pi.z*v.z) - v.w;
            if (pos != srow) {
              unsigned long long k = kpack(s, pos);
              if (k < prev && k > best) best = k;
            }
          }
          #pragma unroll
          for (int off = 1; off < 64; off <<= 1) {
            unsigned long long o = shflxor64(best, off);
            best = o > best ? o : best;
          }
          if (lane == rd) nbr[i*GK_ + rd] = sjdx[16383 - (int)(best & 16383ull)];
          prev = best;
        }
      }
    }
  }
}

// ---------------- GNN layer 1 fused with proj (readlane matmul) ----------------
__global__ __launch_bounds__(256) void gnn1f_vL(
    const float* __restrict__ pooled, float* __restrict__ hout, const int* __restrict__ nbr,
    const float* __restrict__ pw, const float* __restrict__ pb,
    const float* __restrict__ relw, const float* __restrict__ relb,
    const float* __restrict__ rootw)
{
  __shared__ float wrel[H_*H_], wroot[H_*H_];
  const int tid = threadIdx.x;
  #pragma unroll
  for (int q = 0; q < 16; ++q) {
    int idx = tid + 256*q;
    wrel[idx]  = relw[idx];
    wroot[idx] = rootw[idx];
  }
  __syncthreads();

  const int lane = tid & 63;
  const int wave = tid >> 6;
  const int b = blockIdx.y;
  const int m0 = blockIdx.x * 16 + wave * 4;
  const float* pldb = pooled + (size_t)b * M_;
  const float pwl = pw[lane], pbl = pb[lane], rbl = relb[lane];

  float h[4], agg[4], acc[4];
  #pragma unroll
  for (int t = 0; t < 4; ++t) {
    int m = m0 + t;
    float ps = pldb[m];
    h[t] = fmaxf(ps*pwl + pbl, 0.f);
    float a = 0.f;
    #pragma unroll
    for (int k = 0; k < GK_; ++k) {
      int nb = nbr[m*GK_ + k];
      nb = nb < 0 ? 0 : (nb >= M_ ? M_-1 : nb);
      float pn = pldb[nb];
      a += fmaxf(pn*pwl + pbl, 0.f);
    }
    agg[t] = a;
    acc[t] = rbl;
  }
  #pragma unroll
  for (int c = 0; c < H_; ++c) {
    float wr = wrel[c*H_ + lane], wo = wroot[c*H_ + lane];
    #pragma unroll
    for (int t = 0; t < 4; ++t)
      acc[t] += rdlane(agg[t], c) * wr + rdlane(h[t], c) * wo;
  }
  #pragma unroll
  for (int t = 0; t < 4; ++t)
    hout[((size_t)b*M_ + m0 + t)*H_ + lane] = fmaxf(acc[t], 0.f);
}

// ---------------- GNN layer (generic, readlane matmul) ----------------
__global__ __launch_bounds__(256) void gnn_vL(
    const float* __restrict__ hin, float* __restrict__ hout, const int* __restrict__ nbr,
    const float* __restrict__ relw, const float* __restrict__ relb,
    const float* __restrict__ rootw)
{
  __shared__ float wrel[H_*H_], wroot[H_*H_];
  const int tid = threadIdx.x;
  #pragma unroll
  for (int q = 0; q < 16; ++q) {
    int idx = tid + 256*q;
    wrel[idx]  = relw[idx];
    wroot[idx] = rootw[idx];
  }
  __syncthreads();

  const int lane = tid & 63;
  const int wave = tid >> 6;
  const int b = blockIdx.y;
  const int m0 = blockIdx.x * 16 + wave * 4;
  const float* hb = hin + (size_t)b * M_ * H_;
  const float rbl = relb[lane];

  float h[4], agg[4], acc[4];
  #pragma unroll
  for (int t = 0; t < 4; ++t) {
    int m = m0 + t;
    h[t] = hb[m*H_ + lane];
    float a = 0.f;
    #pragma unroll
    for (int k = 0; k < GK_; ++k) {
      int nb = nbr[m*GK_ + k];
      nb = nb < 0 ? 0 : (nb >= M_ ? M_-1 : nb);
      a += hb[nb*H_ + lane];
    }
    agg[t] = a;
    acc[t] = rbl;
  }
  #pragma unroll
  for (int c = 0; c < H_; ++c) {
    float wr = wrel[c*H_ + lane], wo = wroot[c*H_ + lane];
    #pragma unroll
    for (int t = 0; t < 4; ++t)
      acc[t] += rdlane(agg[t], c) * wr + rdlane(h[t], c) * wo;
  }
  #pragma unroll
  for (int t = 0; t < 4; ++t)
    hout[((size_t)b*M_ + m0 + t)*H_ + lane] = fmaxf(acc[t], 0.f);
}

// ---------------- GNN layer 3 + fused global-mean reduce ----------------
__global__ __launch_bounds__(256) void gnn3r_vL(
    const float* __restrict__ hin, float* __restrict__ gf, const int* __restrict__ nbr,
    const float* __restrict__ relw, const float* __restrict__ relb,
    const float* __restrict__ rootw)
{
  __shared__ float wrel[H_*H_], wroot[H_*H_];
  __shared__ float gacc[H_];
  const int tid = threadIdx.x;
  #pragma unroll
  for (int q = 0; q < 16; ++q) {
    int idx = tid + 256*q;
    wrel[idx]  = relw[idx];
    wroot[idx] = rootw[idx];
  }
  if (tid < H_) gacc[tid] = 0.f;
  __syncthreads();

  const int lane = tid & 63;
  const int wave = tid >> 6;
  const int b = blockIdx.y;
  const int m0 = blockIdx.x * 16 + wave * 4;
  const float* hb = hin + (size_t)b * M_ * H_;
  const float rbl = relb[lane];

  float h[4], agg[4], acc[4];
  #pragma unroll
  for (int t = 0; t < 4; ++t) {
    int m = m0 + t;
    h[t] = hb[m*H_ + lane];
    float a = 0.f;
    #pragma unroll
    for (int k = 0; k < GK_; ++k) {
      int nb = nbr[m*GK_ + k];
      nb = nb < 0 ? 0 : (nb >= M_ ? M_-1 : nb);
      a += hb[nb*H_ + lane];
    }
    agg[t] = a;
    acc[t] = rbl;
  }
  #pragma unroll
  for (int c = 0; c < H_; ++c) {
    float wr = wrel[c*H_ + lane], wo = wroot[c*H_ + lane];
    #pragma unroll
    for (int t = 0; t < 4; ++t)
      acc[t] += rdlane(agg[t], c) * wr + rdlane(h[t], c) * wo;
  }
  float ps = fmaxf(acc[0], 0.f) + fmaxf(acc[1], 0.f) + fmaxf(acc[2], 0.f) + fmaxf(acc[3], 0.f);
  atomicAdd(&gacc[lane], ps);
  __syncthreads();
  if (tid < H_) atomicAdd(&gf[b*H_ + tid], gacc[tid]);
}

// ---------------- head ----------------
__global__ __launch_bounds__(256) void head_vL(
    const float* __restrict__ gf, const float* __restrict__ w1,
    const float* __restrict__ b1, const float* __restrict__ w2,
    const float* __restrict__ b2, float* __restrict__ out)
{
  __shared__ float gfm[B_][H_], hid[B_][H_];
  const int tid = threadIdx.x;
  if (tid < B_*H_) gfm[tid >> 6][tid & 63] = gf[tid] * (1.f / (float)M_);
  __syncthreads();
  if (tid < B_*H_) {
    int b = tid >> 6, j = tid & 63;
    float acc = b1[j];
    for (int c = 0; c < H_; ++c) acc += gfm[b][c] * w1[c*H_ + j];
    hid[b][j] = fmaxf(acc, 0.f);
  }
  __syncthreads();
  for (int t = tid; t < B_*NC_; t += 256) {
    int b = t / NC_, o = t - b*NC_;
    float acc = b2[o];
    for (int j = 0; j < H_; ++j) acc += hid[b][j] * w2[j*NC_ + o];
    out[t] = acc;
  }
}

extern "C" void kernel_launch(void* const* d_in, const int* in_sizes, int n_in,
                              void* d_out, int out_size, void* d_ws, size_t ws_size,
                              hipStream_t stream)
{
  float* out = (float*)d_out;

  const size_t need = (size_t)M_*16 + (size_t)B_*N_*16 + (size_t)B_*M_*4
                    + (size_t)M_*GK_*4 + 2*(size_t)B_*M_*H_*4 + (size_t)B_*H_*4;
  bool ok_ws = ws_size >= need;
  bool ok_in = (n_in == 15) && (out_size == B_*NC_)
            && in_sizes[0] == B_*3*N_ && in_sizes[1] == M_*2
            && in_sizes[2] == 2*SH_ && in_sizes[5] == 1
            && in_sizes[8] == 3*H_*H_ && in_sizes[13] == H_*NC_;
  if (!ok_ws || !ok_in) {
    sentinel_vL<<<(out_size + 255)/256, 256, 0, stream>>>(out, out_size, ok_in ? 42.f : 43.f);
    return;
  }

  const float* xxx    = (const float*)d_in[0];
  const float* pix    = (const float*)d_in[1];
  const float* att_w1 = (const float*)d_in[2];
  const float* att_b1 = (const float*)d_in[3];
  const float* att_w2 = (const float*)d_in[4];
  const float* att_b2 = (const float*)d_in[5];
  const float* proj_w = (const float*)d_in[6];
  const float* proj_b = (const float*)d_in[7];
  const float* rel_w  = (const float*)d_in[8];
  const float* rel_b  = (const float*)d_in[9];
  const float* root_w = (const float*)d_in[10];
  const float* out_w1 = (const float*)d_in[11];
  const float* out_b1 = (const float*)d_in[12];
  const float* out_w2 = (const float*)d_in[13];
  const float* out_b2 = (const float*)d_in[14];

  char* w = (char*)d_ws;
  float4* r_pix = (float4*)w;  w += (size_t)M_ * 16;
  float4* r_los = (float4*)w;  w += (size_t)B_ * N_ * 16;
  float*  pooled = (float*)w;  w += (size_t)B_ * M_ * 4;
  int*    nbr = (int*)w;       w += (size_t)M_ * GK_ * 4;
  float*  h0 = (float*)w;      w += (size_t)B_ * M_ * H_ * 4;
  float*  h1 = (float*)w;      w += (size_t)B_ * M_ * H_ * 4;
  float*  gf = (float*)w;      w += (size_t)B_ * H_ * 4;

  // sort/threshold scratch aliases h0 (dead until gnn layer 2 writes it)
  float*  kthrG = h0;                                  // 257 grid thresholds (knn)
  float*  cthrG = h0 + 512;                            // 257 grid thresholds (sampler)
  float4* spix = (float4*)(h0 + 2*M_);                 // M float4
  int*    sjdx = (int*)(h0 + 6*M_);                    // M
  float4* slos = (float4*)(h0 + 7*M_);                 // B*N float4
  unsigned* cnt = (unsigned*)(h0 + 7*M_ + 5*B_*N_);    // 768
  int*    pstart = (int*)(cnt + 768);                  // 257
  int*    lstart = pstart + 257;                       // 2*257
  unsigned* pcur = (unsigned*)(lstart + 514);          // 256
  unsigned* lcur = pcur + 256;                         // 512

  hipMemsetAsync(cnt, 0, 768*sizeof(unsigned), stream);
  prep_vL<<<GRIDB_ + PREPB_, 256, 0, stream>>>(xxx, pix, r_pix, r_los, gf, kthrG, cthrG, cnt);
  scan_vL<<<1, 256, 0, stream>>>(cnt, pstart, lstart, pcur, lcur);
  scatter_vL<<<(M_ + B_*N_ + 255)/256, 256, 0, stream>>>(xxx, pix, r_pix, r_los, pcur, lcur,
                                                         spix, sjdx, slos);
  sampknn_vL<<<dim3(M_/16, B_ + 1), 512, 0, stream>>>(pix, spix, sjdx, slos, lstart, pstart,
                                                      cthrG, kthrG, att_w1, att_b1, att_w2, att_b2,
                                                      pooled, nbr);
  gnn1f_vL<<<dim3(M_/16, B_), 256, 0, stream>>>(pooled, h1, nbr, proj_w, proj_b,
                                                rel_w + 0*H_*H_, rel_b + 0*H_, root_w + 0*H_*H_);
  gnn_vL<<<dim3(M_/16, B_), 256, 0, stream>>>(h1, h0, nbr, rel_w + 1*H_*H_, rel_b + 1*H_, root_w + 1*H_*H_);
  gnn3r_vL<<<dim3(M_/16, B_), 256, 0, stream>>>(h0, gf, nbr, rel_w + 2*H_*H_, rel_b + 2*H_, root_w + 2*H_*H_);
  head_vL<<<1, 256, 0, stream>>>(gf, out_w1, out_b1, out_w2, out_b2, out);
}

// Round 8
// 238.892 us; speedup vs baseline: 1.1016x; 1.0190x over previous
//
#include <hip/hip_runtime.h>
#include <hip/hip_bf16.h>

#define B_ 2
#define N_ 4096
#define M_ 12288
#define K_ 64
#define SH_ 32
#define H_ 64
#define GK_ 8
#define NC_ 200

#define KCAP 128       // knn candidate cap (E=40, +13 sigma)
#define BCAP2 48       // sampler boundary cap
#define SCAP 144       // sampler stored-candidate cap (E=96, +4.9 sigma; overflow -> slow path)
#define MG_ 0.01f      // theta-window safety margin (rad)
#define C256_ 81.48733086f   // 256/pi

static __device__ __forceinline__ unsigned f2key(float f) {
  unsigned b = __float_as_uint(f);
  return (b & 0x80000000u) ? ~b : (b | 0x80000000u);
}
static __device__ __forceinline__ float key2f(unsigned u) {
  unsigned b = (u & 0x80000000u) ? (u & 0x7fffffffu) : ~u;
  return __uint_as_float(b);
}
static __device__ __forceinline__ unsigned long long shflxor64(unsigned long long x, int m) {
  unsigned lo = (unsigned)x, hi = (unsigned)(x >> 32);
  lo = (unsigned)__shfl_xor((int)lo, m);
  hi = (unsigned)__shfl_xor((int)hi, m);
  return ((unsigned long long)hi << 32) | lo;
}
// keys carry SORTED positions (known from loop counter; no index load in scans)
static __device__ __forceinline__ unsigned long long kpack(float s, int pos) {
  return ((unsigned long long)f2key(s) << 14) | (unsigned)(16383 - pos);
}
static __device__ __forceinline__ unsigned long long spack(float c, int pos) {
  return ((unsigned long long)f2key(c) << 12) | (unsigned)(4095 - pos);
}
static __device__ __forceinline__ int thbkt(float th) {
  int b = (int)(th * C256_);
  return b < 0 ? 0 : (b > 255 ? 255 : b);
}
static __device__ __forceinline__ float clamp1(float x) { return fminf(1.f, fmaxf(-1.f, x)); }
static __device__ __forceinline__ float rdlane(float v, int c) {
  return __uint_as_float((unsigned)__builtin_amdgcn_readlane((int)__float_as_uint(v), c));
}

// ---------------- sentinel ----------------
__global__ __launch_bounds__(256) void sentinel_vM(float* out, int n, float val) {
  int t = blockIdx.x * 256 + threadIdx.x;
  if (t < n) out[t] = val;
}

// ---------------- prep + GRID thresholds (257-pt theta grid) + theta-band hist ----------------
#define GRIDB_ 129     // 129 blocks x 4 waves = 516 jobs >= 2*257
#define PREPN_ (M_ + B_*N_ + B_*H_)
#define PREPB_ ((PREPN_ + 255)/256)

__global__ __launch_bounds__(256) void prep_vM(
    const float* __restrict__ xxx, const float* __restrict__ pix,
    float4* __restrict__ r_pix, float4* __restrict__ r_los, float* __restrict__ gf,
    float* __restrict__ kthrG, float* __restrict__ cthrG, unsigned* __restrict__ cnt)
{
  const float PI = 3.14159265358979f;
  if ((int)blockIdx.x < GRIDB_) {
    int gid  = blockIdx.x*4 + (threadIdx.x >> 6);
    if (gid >= 514) return;
    int lane = threadIdx.x & 63;
    int tgt  = (gid >= 257) ? 1 : 0;
    int gp   = gid - tgt*257;
    float thp = (float)gp * (PI/256.f);
    float cp = cosf(thp), sp = fmaxf(sinf(thp), 1e-6f);
    float thq = ((float)lane + 0.5f) * (PI/64.f);
    float sq = sinf(thq), cq = cosf(thq);
    float rinv = 1.0f / (sq * sp);
    // E targets: sampler 96 of N, knn 40 of M (top-K invariant to threshold while count>=K;
    // retry ladder covers the ~5e-4 under-count tail)
    float At = tgt ? (2.f*PI*PI*96.f/(float)N_) : (2.f*PI*PI*40.f/(float)M_);
    float lo = 1e-3f, hi = 3.1414f;
    for (int it = 0; it < 12; ++it) {
      float al = 0.5f*(lo + hi);
      float ca = cosf(al);
      float arg = clamp1((ca - cq*cp) * rinv);
      float ax = fabsf(arg);
      float ac = sqrtf(fmaxf(0.f, 1.f - ax)) *
                 fmaf(ax, fmaf(ax, fmaf(ax, -0.0187293f, 0.0742610f), -0.2121144f), 1.5707288f);
      ac = (arg < 0.f) ? (PI - ac) : ac;
      float S = ac;
      #pragma unroll
      for (int off = 32; off; off >>= 1) S += __shfl_xor(S, off);
      float A = 2.f * S * (PI/64.f);
      if (A < At) lo = al; else hi = al;
    }
    if (lane == 0) {
      float chv = cosf(hi);
      if (tgt) cthrG[gp] = chv - 1e-5f;
      else     kthrG[gp] = 2.f*chv - 1.00002f;
    }
  } else {
    int tid = ((int)blockIdx.x - GRIDB_)*256 + threadIdx.x;
    if (tid < M_) {
      float th = pix[2*tid], ph = pix[2*tid+1];
      float st = sinf(th);
      float x = st*cosf(ph), y = st*sinf(ph), z = cosf(th);
      r_pix[tid] = make_float4(x, y, z, x*x + y*y + z*z);
      atomicAdd(&cnt[thbkt(th)], 1u);
    }
    int t2 = tid - M_;
    if (t2 >= 0 && t2 < B_*N_) {
      int b = t2 >> 12, n = t2 & (N_-1);
      const float* xb = xxx + b*3*N_;
      float th = xb[n], ph = xb[N_+n], ft = xb[2*N_+n];
      float st = sinf(th);
      r_los[t2] = make_float4(st*cosf(ph), st*sinf(ph), cosf(th), ft);
      atomicAdd(&cnt[256 + b*256 + thbkt(th)], 1u);
    }
    int t3 = tid - M_ - B_*N_;
    if (t3 >= 0 && t3 < B_*H_) gf[t3] = 0.0f;
  }
}

// ---------------- scan ----------------
__global__ __launch_bounds__(256) void scan_vM(
    const unsigned* __restrict__ cnt, int* __restrict__ pstart, int* __restrict__ lstart,
    unsigned* __restrict__ pcur, unsigned* __restrict__ lcur)
{
  __shared__ unsigned buf[256];
  const int t = threadIdx.x;
  for (int arr = 0; arr < 3; ++arr) {
    unsigned v = cnt[arr*256 + t];
    buf[t] = v;
    __syncthreads();
    for (int off = 1; off < 256; off <<= 1) {
      unsigned o = (t >= off) ? buf[t - off] : 0u;
      __syncthreads();
      buf[t] += o;
      __syncthreads();
    }
    unsigned incl = buf[t], excl = incl - v;
    if (arr == 0) {
      pstart[t] = (int)excl; if (t == 255) pstart[256] = (int)incl;
      pcur[t] = excl;
    } else {
      int b = arr - 1;
      lstart[b*257 + t] = (int)excl; if (t == 255) lstart[b*257 + 256] = (int)incl;
      lcur[b*256 + t] = excl;
    }
    __syncthreads();
  }
}

// ---------------- scatter (sldx not needed: sampler keys carry sorted pos) -------------
__global__ __launch_bounds__(256) void scatter_vM(
    const float* __restrict__ xxx, const float* __restrict__ pix,
    const float4* __restrict__ r_pix, const float4* __restrict__ r_los,
    unsigned* __restrict__ pcur, unsigned* __restrict__ lcur,
    float4* __restrict__ spix, int* __restrict__ sjdx,
    float4* __restrict__ slos)
{
  int tid = blockIdx.x * 256 + threadIdx.x;
  if (tid < M_) {
    int bkt = thbkt(pix[2*tid]);
    unsigned pos = atomicAdd(&pcur[bkt], 1u);
    spix[pos] = r_pix[tid];
    sjdx[pos] = tid;
  } else {
    int t2 = tid - M_;
    if (t2 < B_*N_) {
      int b = t2 >> 12, n = t2 & (N_-1);
      int bkt = thbkt(xxx[b*3*N_ + n]);
      unsigned pos = atomicAdd(&lcur[b*256 + bkt], 1u);
      slos[b*N_ + pos] = r_los[t2];
    }
  }
}

// ---------------- sampler vM: vJ structure; clamp dropped in hot scan (predicate/key/bin
// ---------------- all invariant: th<1, f2key monotone, 1-th >= 0.045 >> dot rounding) ---------
__global__ __launch_bounds__(512) void sampler_vM(
    const float* __restrict__ pix,
    const float4* __restrict__ spix, const int* __restrict__ sjdx,
    const float4* __restrict__ slos,
    const int* __restrict__ lstart,
    const float* __restrict__ cthrG,
    const float* __restrict__ aw1, const float* __restrict__ ab1,
    const float* __restrict__ aw2, const float* __restrict__ ab2,
    float* __restrict__ pooled)
{
  __shared__ unsigned long long cand[16][SCAP];     // 18 KB
  __shared__ unsigned long long selKey[16][K_];     // 8 KB
  __shared__ unsigned long long bndK[16][BCAP2];    // 6 KB
  __shared__ unsigned hist[16][64];                 // 4 KB   -> 36 KB total, 4 blocks/CU

  const int tid = threadIdx.x, wv = tid >> 6, lane = tid & 63;
  const int b  = blockIdx.y;
  const int srow0 = blockIdx.x*16 + wv*2, srow1 = srow0 + 1;
  const int r0 = wv*2, r1 = r0 + 1;
  const int m0 = sjdx[srow0], m1 = sjdx[srow1];
  const float4 p0 = spix[srow0], p1 = spix[srow1];
  const float thp0 = pix[2*m0], thp1 = pix[2*m1];
  const int g0 = thbkt(thp0), g1 = thbkt(thp1);
  const float th0 = fminf(cthrG[g0], cthrG[g0+1]);
  const float th1 = fminf(cthrG[g1], cthrG[g1+1]);
  const float inv0 = 63.999f / (1.000001f - th0);
  const float inv1 = 63.999f / (1.000001f - th1);
  const float4* sl = slos + b * N_;
  const int* ls = lstart + b * 257;
  const unsigned long long ltm = (1ull << lane) - 1ull;

  // union window bounds
  int jlo, jhi;
  {
    float al0 = acosf(clamp1(th0)), al1 = acosf(clamp1(th1));
    int blo = thbkt(fminf(thp0 - al0, thp1 - al1) - MG_);
    int bhi = thbkt(fmaxf(thp0 + al0, thp1 + al1) + MG_);
    jlo = ls[blo]; jhi = ls[bhi + 1];
  }

  // single pass: dot, predicate, compact candidates of both rows into LDS (pos-keys, no clamp)
  unsigned cnt0 = 0, cnt1 = 0;
  for (int base = jlo; base < jhi; base += 64) {
    int pos = base + lane;
    bool act = pos < jhi;
    float c0 = -2.f, c1 = -2.f;
    if (act) {
      float4 v = sl[pos];
      c0 = v.x*p0.x + v.y*p0.y + v.z*p0.z;
      c1 = v.x*p1.x + v.y*p1.y + v.z*p1.z;
    }
    bool pr0 = c0 > th0, pr1 = c1 > th1;
    unsigned long long mk0 = __ballot(pr0);
    if (mk0) {
      unsigned off = (unsigned)__popcll(mk0 & ltm);
      if (pr0 && cnt0 + off < SCAP) cand[r0][cnt0 + off] = spack(c0, pos);
      cnt0 += (unsigned)__popcll(mk0);
    }
    unsigned long long mk1 = __ballot(pr1);
    if (mk1) {
      unsigned off = (unsigned)__popcll(mk1 & ltm);
      if (pr1 && cnt1 + off < SCAP) cand[r1][cnt1 + off] = spack(c1, pos);
      cnt1 += (unsigned)__popcll(mk1);
    }
  }

  for (int rr = 0; rr < 2; ++rr) {
    const int r = (rr == 0) ? r0 : r1;
    const int m = (rr == 0) ? m0 : m1;
    const float4 p = (rr == 0) ? p0 : p1;
    const float thp = (rr == 0) ? thp0 : thp1;
    const float thg = (rr == 0) ? th0 : th1;
    const float invg = (rr == 0) ? inv0 : inv1;
    unsigned cn = (rr == 0) ? cnt0 : cnt1;
    bool fin = false;

    // fast path: all candidates captured in LDS -> select without touching global
    if (cn >= (unsigned)K_ && cn <= (unsigned)SCAP) {
      hist[r][lane] = 0u;
      for (int i = lane; i < (int)cn; i += 64) {
        float c = key2f((unsigned)(cand[r][i] >> 12));
        atomicAdd(&hist[r][(int)((c - thg) * invg)], 1u);
      }
      unsigned g = hist[r][lane], s = g;
      #pragma unroll
      for (int off = 1; off < 64; off <<= 1) {
        unsigned t2 = (unsigned)__shfl_down((int)s, off);
        s += (lane + off < 64) ? t2 : 0u;
      }
      unsigned snext = s - g;
      unsigned packed = (s >= K_ && snext < K_) ? (((unsigned)(lane+1) << 16) | snext) : 0u;
      #pragma unroll
      for (int off = 32; off; off >>= 1) {
        unsigned o = (unsigned)__shfl_xor((int)packed, off);
        packed = packed > o ? packed : o;
      }
      const int t = (int)(packed >> 16) - 1;
      const unsigned chi = packed & 0xFFFFu;
      const unsigned need = K_ - chi;

      unsigned hiC = 0, bdC = 0;
      for (int i0 = 0; i0 < (int)cn; i0 += 64) {
        int i = i0 + lane;
        bool act = i < (int)cn;
        unsigned long long key = act ? cand[r][i] : 0ull;
        int bin = -1;
        if (act) bin = (int)((key2f((unsigned)(key >> 12)) - thg) * invg);
        bool pHi = act && bin > t, pBd = act && bin == t;
        unsigned long long mH = __ballot(pHi);
        unsigned offH = (unsigned)__popcll(mH & ltm);
        if (pHi && hiC + offH < K_) selKey[r][hiC + offH] = key;
        hiC += (unsigned)__popcll(mH);
        unsigned long long mB = __ballot(pBd);
        unsigned offB = (unsigned)__popcll(mB & ltm);
        if (pBd && bdC + offB < BCAP2) bndK[r][bdC + offB] = key;
        bdC += (unsigned)__popcll(mB);
      }
      if (bdC <= (unsigned)BCAP2) {
        if (lane < (int)bdC) {
          unsigned long long ki = bndK[r][lane];
          int rank = 0;
          for (int j = 0; j < (int)bdC; ++j) rank += (bndK[r][j] > ki) ? 1 : 0;
          if ((unsigned)rank < need) selKey[r][chi + rank] = ki;
        }
        fin = true;
      }
    }

    if (!fin) {
      // slow path (rare: candidate overflow, boundary overflow, or under-count)
      float th = thg;
      float inv = invg;
      int wlo = jlo, whi = jhi;

      if (cn >= (unsigned)K_) {
        // overflow case: rebuild hist over the window at the base threshold
        hist[r][lane] = 0u;
        cn = 0;
        for (int base = wlo; base < whi; base += 64) {
          int pos = base + lane;
          bool act = pos < whi;
          float c = -2.f;
          if (act) {
            float4 v = sl[pos];
            c = clamp1(v.x*p.x + v.y*p.y + v.z*p.z);
          }
          bool pr = c > th;
          if (pr) atomicAdd(&hist[r][(int)((c - th) * inv)], 1u);
          cn += (unsigned)__popcll(__ballot(pr));
        }
      }

      int tries = 0;
      while (cn < K_ && tries < 3) {
        th = 1.f - 1.6f*(1.f - th); ++tries;
        inv = 63.999f / (1.000001f - th);
        float al = acosf(clamp1(th));
        int blo = thbkt(thp - al - MG_), bhi = thbkt(thp + al + MG_);
        wlo = ls[blo]; whi = ls[bhi + 1];
        hist[r][lane] = 0u;
        cn = 0;
        for (int base = wlo; base < whi; base += 64) {
          int pos = base + lane;
          bool act = pos < whi;
          float c = -2.f;
          if (act) {
            float4 v = sl[pos];
            c = clamp1(v.x*p.x + v.y*p.y + v.z*p.z);
          }
          bool pr = c > th;
          if (pr) atomicAdd(&hist[r][(int)((c - th) * inv)], 1u);
          cn += (unsigned)__popcll(__ballot(pr));
        }
      }

      bool fin2 = false;
      if (cn >= K_) {
        unsigned g = hist[r][lane], s = g;
        #pragma unroll
        for (int off = 1; off < 64; off <<= 1) {
          unsigned t2 = (unsigned)__shfl_down((int)s, off);
          s += (lane + off < 64) ? t2 : 0u;
        }
        unsigned snext = s - g;
        unsigned packed = (s >= K_ && snext < K_) ? (((unsigned)(lane+1) << 16) | snext) : 0u;
        #pragma unroll
        for (int off = 32; off; off >>= 1) {
          unsigned o = (unsigned)__shfl_xor((int)packed, off);
          packed = packed > o ? packed : o;
        }
        const int t = (int)(packed >> 16) - 1;
        const unsigned chi = packed & 0xFFFFu;
        const unsigned need = K_ - chi;

        unsigned hiC = 0, bdC = 0;
        for (int base = wlo; base < whi; base += 64) {
          int pos = base + lane;
          bool act = pos < whi;
          float c = -2.f;
          if (act) {
            float4 v = sl[pos];
            c = clamp1(v.x*p.x + v.y*p.y + v.z*p.z);
          }
          int bin = (act && c > th) ? (int)((c - th) * inv) : -1;
          bool pHi = bin > t;
          bool pBd = bin == t;
          unsigned long long mH = __ballot(pHi);
          unsigned offH = (unsigned)__popcll(mH & ltm);
          if (pHi && hiC + offH < K_) selKey[r][hiC + offH] = spack(c, pos);
          hiC += (unsigned)__popcll(mH);
          unsigned long long mB = __ballot(pBd);
          unsigned offB = (unsigned)__popcll(mB & ltm);
          if (pBd && bdC + offB < BCAP2) bndK[r][bdC + offB] = spack(c, pos);
          bdC += (unsigned)__popcll(mB);
        }
        if (bdC <= (unsigned)BCAP2) {
          if (lane < (int)bdC) {
            unsigned long long ki = bndK[r][lane];
            int rank = 0;
            for (int j = 0; j < (int)bdC; ++j) rank += (bndK[r][j] > ki) ? 1 : 0;
            if ((unsigned)rank < need) selKey[r][chi + rank] = ki;
          }
          fin2 = true;
        }
      }

      if (!fin2) {
        // ultimate fallback: exact top-K over the sorted array (pos-keys)
        unsigned long long prev = ~0ull;
        for (int rd = 0; rd < K_; ++rd) {
          unsigned long long best = 0ull;
          for (int i = 0; i < 64; ++i) {
            int pos = lane + 64*i;
            float4 v = sl[pos];
            float c = clamp1(v.x*p.x + v.y*p.y + v.z*p.z);
            unsigned long long k = spack(c, pos);
            if (k < prev && k > best) best = k;
          }
          #pragma unroll
          for (int off = 1; off < 64; off <<= 1) {
            unsigned long long o = shflxor64(best, off);
            best = o > best ? o : best;
          }
          if (lane == 0) selKey[r][rd] = best;
          prev = best;
        }
      }
    }

    // attention MLP + softmax + weighted pool (decode pos; feature from slos.w)
    {
      unsigned long long key = selKey[r][lane];
      int pos = 4095 - (int)(key & 0xFFFull);
      float c = key2f((unsigned)(key >> 12));
      float xg = sl[pos].w;
      float d  = acosf(clamp1(c));
      float acc = ab2[0];
      for (int s2 = 0; s2 < SH_; ++s2)
        acc += fmaxf(xg*aw1[s2] + d*aw1[SH_+s2] + ab1[s2], 0.f) * aw2[s2];
      float mx = acc;
      #pragma unroll
      for (int off = 32; off; off >>= 1) mx = fmaxf(mx, __shfl_xor(mx, off));
      float e = expf(acc - mx);
      float se = e, sxe = e * xg;
      #pragma unroll
      for (int off = 32; off; off >>= 1) { se += __shfl_xor(se, off); sxe += __shfl_xor(sxe, off); }
      if (lane == 0) pooled[b*M_ + m] = sxe / se;
    }
  }
}

// ---------------- knn vM (pos-keys, no index load in scan; decode via sjdx at write) ---------
__global__ __launch_bounds__(512) void knn_vM(
    const float* __restrict__ pix,
    const float4* __restrict__ spix, const int* __restrict__ sjdx,
    const int* __restrict__ pstart,
    const float* __restrict__ kthrG, int* __restrict__ nbr)
{
  __shared__ unsigned long long cKey[16][KCAP];

  const int tid = threadIdx.x, wv = tid >> 6, lane = tid & 63;
  const int lr0 = wv*2;
  const int srow0 = blockIdx.x*16 + lr0, srow1 = srow0 + 1;
  const int i0 = sjdx[srow0], i1 = sjdx[srow1];
  const float4 p0 = spix[srow0], p1 = spix[srow1];
  const float thp0 = pix[2*i0], thp1 = pix[2*i1];
  const int g0 = thbkt(thp0), g1 = thbkt(thp1);
  const float t0 = fminf(kthrG[g0], kthrG[g0+1]);
  const float t1 = fminf(kthrG[g1], kthrG[g1+1]);
  const unsigned long long ltm = (1ull << lane) - 1ull;

  unsigned cnt0 = 0, cnt1 = 0;
  {
    float al0 = acosf(clamp1((t0 + 1.00002f)*0.5f));
    float al1 = acosf(clamp1((t1 + 1.00002f)*0.5f));
    int blo = thbkt(fminf(thp0 - al0, thp1 - al1) - MG_);
    int bhi = thbkt(fmaxf(thp0 + al0, thp1 + al1) + MG_);
    int jlo = pstart[blo], jhi = pstart[bhi + 1];
    for (int base = jlo; base < jhi; base += 64) {
      int pos = base + lane;
      bool act = pos < jhi;
      float s0 = -1e30f, s1 = -1e30f;
      if (act) {
        float4 v = spix[pos];
        s0 = 2.f*(p0.x*v.x + p0.y*v.y + p0.z*v.z) - v.w;
        s1 = 2.f*(p1.x*v.x + p1.y*v.y + p1.z*v.z) - v.w;
      }
      bool pr0 = act && (pos != srow0) && (s0 > t0);
      bool pr1 = act && (pos != srow1) && (s1 > t1);
      unsigned long long mk0 = __ballot(pr0);
      if (mk0) {
        unsigned off = (unsigned)__popcll(mk0 & ltm);
        if (pr0 && cnt0 + off < KCAP) cKey[lr0][cnt0 + off] = kpack(s0, pos);
        cnt0 += (unsigned)__popcll(mk0);
      }
      unsigned long long mk1 = __ballot(pr1);
      if (mk1) {
        unsigned off = (unsigned)__popcll(mk1 & ltm);
        if (pr1 && cnt1 + off < KCAP) cKey[lr0+1][cnt1 + off] = kpack(s1, pos);
        cnt1 += (unsigned)__popcll(mk1);
      }
    }
  }

  for (int rr = 0; rr < 2; ++rr) {
    const int lr = lr0 + rr;
    const int i  = (rr == 0) ? i0 : i1;
    const int srow = (rr == 0) ? srow0 : srow1;
    const float4 pi = (rr == 0) ? p0 : p1;
    const float thp = (rr == 0) ? thp0 : thp1;
    float th = (rr == 0) ? t0 : t1;
    unsigned cn = (rr == 0) ? cnt0 : cnt1;

    int tries = 0;
    while (cn < (unsigned)GK_ && tries < 3) {
      th = 1.6f*th - 0.6f; ++tries;
      float al = acosf(clamp1((th + 1.00002f)*0.5f));
      int blo = thbkt(thp - al - MG_), bhi = thbkt(thp + al + MG_);
      int jlo = pstart[blo], jhi = pstart[bhi + 1];
      cn = 0;
      for (int base = jlo; base < jhi; base += 64) {
        int pos = base + lane;
        bool act = pos < jhi;
        float s = -1e30f;
        if (act) {
          float4 v = spix[pos];
          s = 2.f*(pi.x*v.x + pi.y*v.y + pi.z*v.z) - v.w;
        }
        bool pr = act && (pos != srow) && (s > th);
        unsigned long long mk = __ballot(pr);
        if (mk) {
          unsigned off = (unsigned)__popcll(mk & ltm);
          if (pr && cn + off < KCAP) cKey[lr][cn + off] = kpack(s, pos);
          cn += (unsigned)__popcll(mk);
        }
      }
    }

    if (cn >= (unsigned)GK_ && cn <= (unsigned)KCAP) {
      unsigned long long pk[2];
      #pragma unroll
      for (int t2 = 0; t2 < 2; ++t2) {
        int idx = lane + 64*t2;
        pk[t2] = (idx < (int)cn) ? cKey[lr][idx] : 0ull;
      }
      for (int round = 0; round < GK_; ++round) {
        unsigned long long loc = pk[0]; int lt = 0;
        if (pk[1] > loc) { loc = pk[1]; lt = 1; }
        unsigned long long best = loc;
        #pragma unroll
        for (int off = 1; off < 64; off <<= 1) {
          unsigned long long o = shflxor64(best, off);
          best = o > best ? o : best;
        }
        if (loc == best) pk[lt] = 0ull;
        if (lane == round) nbr[i*GK_ + round] = sjdx[16383 - (int)(best & 16383ull)];
      }
    } else {
      unsigned long long prev = ~0ull;
      for (int rd = 0; rd < GK_; ++rd) {
        unsigned long long best = 0ull;
        for (int pos = lane; pos < M_; pos += 64) {
          float4 v = spix[pos];
          float s = 2.f*(pi.x*v.x + pi.y*v.y + pi.z*v.z) - v.w;
          if (pos != srow) {
            unsigned long long k = kpack(s, pos);
            if (k < prev && k > best) best = k;
          }
        }
        #pragma unroll
        for (int off = 1; off < 64; off <<= 1) {
          unsigned long long o = shflxor64(best, off);
          best = o > best ? o : best;
        }
        if (lane == rd) nbr[i*GK_ + rd] = sjdx[16383 - (int)(best & 16383ull)];
        prev = best;
      }
    }
  }
}

// ---------------- GNN layer 1 fused with proj (readlane matmul, float4 weight preload) --------
__global__ __launch_bounds__(256) void gnn1f_vM(
    const float* __restrict__ pooled, float* __restrict__ hout, const int* __restrict__ nbr,
    const float* __restrict__ pw, const float* __restrict__ pb,
    const float* __restrict__ relw, const float* __restrict__ relb,
    const float* __restrict__ rootw)
{
  __shared__ float wrel[H_*H_], wroot[H_*H_];
  const int tid = threadIdx.x;
  {
    const float4* rw4 = (const float4*)relw;
    const float4* ow4 = (const float4*)rootw;
    float4* wr4 = (float4*)wrel;
    float4* wo4 = (float4*)wroot;
    #pragma unroll
    for (int q = 0; q < 4; ++q) {
      int idx = tid + 256*q;
      wr4[idx] = rw4[idx];
      wo4[idx] = ow4[idx];
    }
  }
  __syncthreads();

  const int lane = tid & 63;
  const int wave = tid >> 6;
  const int b = blockIdx.y;
  const int m0 = blockIdx.x * 16 + wave * 4;
  const float* pldb = pooled + (size_t)b * M_;
  const float pwl = pw[lane], pbl = pb[lane], rbl = relb[lane];

  float h[4], agg[4], acc[4];
  #pragma unroll
  for (int t = 0; t < 4; ++t) {
    int m = m0 + t;
    float ps = pldb[m];
    h[t] = fmaxf(ps*pwl + pbl, 0.f);
    float a = 0.f;
    #pragma unroll
    for (int k = 0; k < GK_; ++k) {
      int nb = nbr[m*GK_ + k];
      nb = nb < 0 ? 0 : (nb >= M_ ? M_-1 : nb);
      float pn = pldb[nb];
      a += fmaxf(pn*pwl + pbl, 0.f);
    }
    agg[t] = a;
    acc[t] = rbl;
  }
  #pragma unroll
  for (int c = 0; c < H_; ++c) {
    float wr = wrel[c*H_ + lane], wo = wroot[c*H_ + lane];
    #pragma unroll
    for (int t = 0; t < 4; ++t)
      acc[t] += rdlane(agg[t], c) * wr + rdlane(h[t], c) * wo;
  }
  #pragma unroll
  for (int t = 0; t < 4; ++t)
    hout[((size_t)b*M_ + m0 + t)*H_ + lane] = fmaxf(acc[t], 0.f);
}

// ---------------- GNN layer (generic, readlane matmul, float4 weight preload) ----------------
__global__ __launch_bounds__(256) void gnn_vM(
    const float* __restrict__ hin, float* __restrict__ hout, const int* __restrict__ nbr,
    const float* __restrict__ relw, const float* __restrict__ relb,
    const float* __restrict__ rootw)
{
  __shared__ float wrel[H_*H_], wroot[H_*H_];
  const int tid = threadIdx.x;
  {
    const float4* rw4 = (const float4*)relw;
    const float4* ow4 = (const float4*)rootw;
    float4* wr4 = (float4*)wrel;
    float4* wo4 = (float4*)wroot;
    #pragma unroll
    for (int q = 0; q < 4; ++q) {
      int idx = tid + 256*q;
      wr4[idx] = rw4[idx];
      wo4[idx] = ow4[idx];
    }
  }
  __syncthreads();

  const int lane = tid & 63;
  const int wave = tid >> 6;
  const int b = blockIdx.y;
  const int m0 = blockIdx.x * 16 + wave * 4;
  const float* hb = hin + (size_t)b * M_ * H_;
  const float rbl = relb[lane];

  float h[4], agg[4], acc[4];
  #pragma unroll
  for (int t = 0; t < 4; ++t) {
    int m = m0 + t;
    h[t] = hb[m*H_ + lane];
    float a = 0.f;
    #pragma unroll
    for (int k = 0; k < GK_; ++k) {
      int nb = nbr[m*GK_ + k];
      nb = nb < 0 ? 0 : (nb >= M_ ? M_-1 : nb);
      a += hb[nb*H_ + lane];
    }
    agg[t] = a;
    acc[t] = rbl;
  }
  #pragma unroll
  for (int c = 0; c < H_; ++c) {
    float wr = wrel[c*H_ + lane], wo = wroot[c*H_ + lane];
    #pragma unroll
    for (int t = 0; t < 4; ++t)
      acc[t] += rdlane(agg[t], c) * wr + rdlane(h[t], c) * wo;
  }
  #pragma unroll
  for (int t = 0; t < 4; ++t)
    hout[((size_t)b*M_ + m0 + t)*H_ + lane] = fmaxf(acc[t], 0.f);
}

// ---------------- GNN layer 3 + fused global-mean reduce (float4 weight preload) -------------
__global__ __launch_bounds__(256) void gnn3r_vM(
    const float* __restrict__ hin, float* __restrict__ gf, const int* __restrict__ nbr,
    const float* __restrict__ relw, const float* __restrict__ relb,
    const float* __restrict__ rootw)
{
  __shared__ float wrel[H_*H_], wroot[H_*H_];
  __shared__ float gacc[H_];
  const int tid = threadIdx.x;
  {
    const float4* rw4 = (const float4*)relw;
    const float4* ow4 = (const float4*)rootw;
    float4* wr4 = (float4*)wrel;
    float4* wo4 = (float4*)wroot;
    #pragma unroll
    for (int q = 0; q < 4; ++q) {
      int idx = tid + 256*q;
      wr4[idx] = rw4[idx];
      wo4[idx] = ow4[idx];
    }
  }
  if (tid < H_) gacc[tid] = 0.f;
  __syncthreads();

  const int lane = tid & 63;
  const int wave = tid >> 6;
  const int b = blockIdx.y;
  const int m0 = blockIdx.x * 16 + wave * 4;
  const float* hb = hin + (size_t)b * M_ * H_;
  const float rbl = relb[lane];

  float h[4], agg[4], acc[4];
  #pragma unroll
  for (int t = 0; t < 4; ++t) {
    int m = m0 + t;
    h[t] = hb[m*H_ + lane];
    float a = 0.f;
    #pragma unroll
    for (int k = 0; k < GK_; ++k) {
      int nb = nbr[m*GK_ + k];
      nb = nb < 0 ? 0 : (nb >= M_ ? M_-1 : nb);
      a += hb[nb*H_ + lane];
    }
    agg[t] = a;
    acc[t] = rbl;
  }
  #pragma unroll
  for (int c = 0; c < H_; ++c) {
    float wr = wrel[c*H_ + lane], wo = wroot[c*H_ + lane];
    #pragma unroll
    for (int t = 0; t < 4; ++t)
      acc[t] += rdlane(agg[t], c) * wr + rdlane(h[t], c) * wo;
  }
  float ps = fmaxf(acc[0], 0.f) + fmaxf(acc[1], 0.f) + fmaxf(acc[2], 0.f) + fmaxf(acc[3], 0.f);
  atomicAdd(&gacc[lane], ps);
  __syncthreads();
  if (tid < H_) atomicAdd(&gf[b*H_ + tid], gacc[tid]);
}

// ---------------- head ----------------
__global__ __launch_bounds__(256) void head_vM(
    const float* __restrict__ gf, const float* __restrict__ w1,
    const float* __restrict__ b1, const float* __restrict__ w2,
    const float* __restrict__ b2, float* __restrict__ out)
{
  __shared__ float gfm[B_][H_], hid[B_][H_];
  const int tid = threadIdx.x;
  if (tid < B_*H_) gfm[tid >> 6][tid & 63] = gf[tid] * (1.f / (float)M_);
  __syncthreads();
  if (tid < B_*H_) {
    int b = tid >> 6, j = tid & 63;
    float acc = b1[j];
    for (int c = 0; c < H_; ++c) acc += gfm[b][c] * w1[c*H_ + j];
    hid[b][j] = fmaxf(acc, 0.f);
  }
  __syncthreads();
  for (int t = tid; t < B_*NC_; t += 256) {
    int b = t / NC_, o = t - b*NC_;
    float acc = b2[o];
    for (int j = 0; j < H_; ++j) acc += hid[b][j] * w2[j*NC_ + o];
    out[t] = acc;
  }
}

extern "C" void kernel_launch(void* const* d_in, const int* in_sizes, int n_in,
                              void* d_out, int out_size, void* d_ws, size_t ws_size,
                              hipStream_t stream)
{
  float* out = (float*)d_out;

  const size_t need = (size_t)M_*16 + (size_t)B_*N_*16 + (size_t)B_*M_*4
                    + (size_t)M_*GK_*4 + 2*(size_t)B_*M_*H_*4 + (size_t)B_*H_*4;
  bool ok_ws = ws_size >= need;
  bool ok_in = (n_in == 15) && (out_size == B_*NC_)
            && in_sizes[0] == B_*3*N_ && in_sizes[1] == M_*2
            && in_sizes[2] == 2*SH_ && in_sizes[5] == 1
            && in_sizes[8] == 3*H_*H_ && in_sizes[13] == H_*NC_;
  if (!ok_ws || !ok_in) {
    sentinel_vM<<<(out_size + 255)/256, 256, 0, stream>>>(out, out_size, ok_in ? 42.f : 43.f);
    return;
  }

  const float* xxx    = (const float*)d_in[0];
  const float* pix    = (const float*)d_in[1];
  const float* att_w1 = (const float*)d_in[2];
  const float* att_b1 = (const float*)d_in[3];
  const float* att_w2 = (const float*)d_in[4];
  const float* att_b2 = (const float*)d_in[5];
  const float* proj_w = (const float*)d_in[6];
  const float* proj_b = (const float*)d_in[7];
  const float* rel_w  = (const float*)d_in[8];
  const float* rel_b  = (const float*)d_in[9];
  const float* root_w = (const float*)d_in[10];
  const float* out_w1 = (const float*)d_in[11];
  const float* out_b1 = (const float*)d_in[12];
  const float* out_w2 = (const float*)d_in[13];
  const float* out_b2 = (const float*)d_in[14];

  char* w = (char*)d_ws;
  float4* r_pix = (float4*)w;  w += (size_t)M_ * 16;
  float4* r_los = (float4*)w;  w += (size_t)B_ * N_ * 16;
  float*  pooled = (float*)w;  w += (size_t)B_ * M_ * 4;
  int*    nbr = (int*)w;       w += (size_t)M_ * GK_ * 4;
  float*  h0 = (float*)w;      w += (size_t)B_ * M_ * H_ * 4;
  float*  h1 = (float*)w;      w += (size_t)B_ * M_ * H_ * 4;
  float*  gf = (float*)w;      w += (size_t)B_ * H_ * 4;

  // sort/threshold scratch aliases h0 (dead until gnn layer 2 writes it)
  float*  kthrG = h0;                                  // 257 grid thresholds (knn)
  float*  cthrG = h0 + 512;                            // 257 grid thresholds (sampler)
  float4* spix = (float4*)(h0 + 2*M_);                 // M float4
  int*    sjdx = (int*)(h0 + 6*M_);                    // M
  float4* slos = (float4*)(h0 + 7*M_);                 // B*N float4
  unsigned* cnt = (unsigned*)(h0 + 7*M_ + 5*B_*N_);    // 768
  int*    pstart = (int*)(cnt + 768);                  // 257
  int*    lstart = pstart + 257;                       // 2*257
  unsigned* pcur = (unsigned*)(lstart + 514);          // 256
  unsigned* lcur = pcur + 256;                         // 512

  hipMemsetAsync(cnt, 0, 768*sizeof(unsigned), stream);
  prep_vM<<<GRIDB_ + PREPB_, 256, 0, stream>>>(xxx, pix, r_pix, r_los, gf, kthrG, cthrG, cnt);
  scan_vM<<<1, 256, 0, stream>>>(cnt, pstart, lstart, pcur, lcur);
  scatter_vM<<<(M_ + B_*N_ + 255)/256, 256, 0, stream>>>(xxx, pix, r_pix, r_los, pcur, lcur,
                                                         spix, sjdx, slos);
  sampler_vM<<<dim3(M_/16, B_), 512, 0, stream>>>(pix, spix, sjdx, slos, lstart,
                                                  cthrG, att_w1, att_b1, att_w2, att_b2, pooled);
  knn_vM<<<M_/16, 512, 0, stream>>>(pix, spix, sjdx, pstart, kthrG, nbr);
  gnn1f_vM<<<dim3(M_/16, B_), 256, 0, stream>>>(pooled, h1, nbr, proj_w, proj_b,
                                                rel_w + 0*H_*H_, rel_b + 0*H_, root_w + 0*H_*H_);
  gnn_vM<<<dim3(M_/16, B_), 256, 0, stream>>>(h1, h0, nbr, rel_w + 1*H_*H_, rel_b + 1*H_, root_w + 1*H_*H_);
  gnn3r_vM<<<dim3(M_/16, B_), 256, 0, stream>>>(h0, gf, nbr, rel_w + 2*H_*H_, rel_b + 2*H_, root_w + 2*H_*H_);
  head_vM<<<1, 256, 0, stream>>>(gf, out_w1, out_b1, out_w2, out_b2, out);
}

// Round 9
// 235.053 us; speedup vs baseline: 1.1196x; 1.0163x over previous
//
#include <hip/hip_runtime.h>
#include <hip/hip_bf16.h>

#define B_ 2
#define N_ 4096
#define M_ 12288
#define K_ 64
#define SH_ 32
#define H_ 64
#define GK_ 8
#define NC_ 200

#define KCAP 128       // knn candidate cap (E=40, +13 sigma)
#define BCAP2 48       // sampler boundary cap
#define SCAP 144       // sampler stored-candidate cap (E=96, +4.9 sigma; overflow -> slow path)
#define MG_ 0.01f      // theta-window safety margin (rad)
#define C256_ 81.48733086f   // 256/pi

static __device__ __forceinline__ unsigned f2key(float f) {
  unsigned b = __float_as_uint(f);
  return (b & 0x80000000u) ? ~b : (b | 0x80000000u);
}
static __device__ __forceinline__ float key2f(unsigned u) {
  unsigned b = (u & 0x80000000u) ? (u & 0x7fffffffu) : ~u;
  return __uint_as_float(b);
}
static __device__ __forceinline__ unsigned long long shflxor64(unsigned long long x, int m) {
  unsigned lo = (unsigned)x, hi = (unsigned)(x >> 32);
  lo = (unsigned)__shfl_xor((int)lo, m);
  hi = (unsigned)__shfl_xor((int)hi, m);
  return ((unsigned long long)hi << 32) | lo;
}
// keys carry SORTED positions (known from loop counter; no index load in scans)
static __device__ __forceinline__ unsigned long long kpack(float s, int pos) {
  return ((unsigned long long)f2key(s) << 14) | (unsigned)(16383 - pos);
}
static __device__ __forceinline__ unsigned long long spack(float c, int pos) {
  return ((unsigned long long)f2key(c) << 12) | (unsigned)(4095 - pos);
}
static __device__ __forceinline__ int thbkt(float th) {
  int b = (int)(th * C256_);
  return b < 0 ? 0 : (b > 255 ? 255 : b);
}
static __device__ __forceinline__ float clamp1(float x) { return fminf(1.f, fmaxf(-1.f, x)); }
static __device__ __forceinline__ float rdlane(float v, int c) {
  return __uint_as_float((unsigned)__builtin_amdgcn_readlane((int)__float_as_uint(v), c));
}

// ---------------- sentinel ----------------
__global__ __launch_bounds__(256) void sentinel_vN(float* out, int n, float val) {
  int t = blockIdx.x * 256 + threadIdx.x;
  if (t < n) out[t] = val;
}

// ---------------- prep + GRID thresholds (257-pt theta grid) + theta-band hist ----------------
#define GRIDB_ 129     // 129 blocks x 4 waves = 516 jobs >= 2*257
#define PREPN_ (M_ + B_*N_ + B_*H_)
#define PREPB_ ((PREPN_ + 255)/256)

__global__ __launch_bounds__(256) void prep_vN(
    const float* __restrict__ xxx, const float* __restrict__ pix,
    float4* __restrict__ r_pix, float4* __restrict__ r_los, float* __restrict__ gf,
    float* __restrict__ kthrG, float* __restrict__ cthrG, unsigned* __restrict__ cnt)
{
  const float PI = 3.14159265358979f;
  if ((int)blockIdx.x < GRIDB_) {
    int gid  = blockIdx.x*4 + (threadIdx.x >> 6);
    if (gid >= 514) return;
    int lane = threadIdx.x & 63;
    int tgt  = (gid >= 257) ? 1 : 0;
    int gp   = gid - tgt*257;
    float thp = (float)gp * (PI/256.f);
    float cp = cosf(thp), sp = fmaxf(sinf(thp), 1e-6f);
    float thq = ((float)lane + 0.5f) * (PI/64.f);
    float sq = sinf(thq), cq = cosf(thq);
    float rinv = 1.0f / (sq * sp);
    // E targets: sampler 96 of N, knn 40 of M (top-K invariant to threshold while count>=K;
    // retry ladder covers the ~5e-4 under-count tail)
    float At = tgt ? (2.f*PI*PI*96.f/(float)N_) : (2.f*PI*PI*40.f/(float)M_);
    float lo = 1e-3f, hi = 3.1414f;
    for (int it = 0; it < 12; ++it) {
      float al = 0.5f*(lo + hi);
      float ca = cosf(al);
      float arg = clamp1((ca - cq*cp) * rinv);
      float ax = fabsf(arg);
      float ac = sqrtf(fmaxf(0.f, 1.f - ax)) *
                 fmaf(ax, fmaf(ax, fmaf(ax, -0.0187293f, 0.0742610f), -0.2121144f), 1.5707288f);
      ac = (arg < 0.f) ? (PI - ac) : ac;
      float S = ac;
      #pragma unroll
      for (int off = 32; off; off >>= 1) S += __shfl_xor(S, off);
      float A = 2.f * S * (PI/64.f);
      if (A < At) lo = al; else hi = al;
    }
    if (lane == 0) {
      float chv = cosf(hi);
      if (tgt) cthrG[gp] = chv - 1e-5f;
      else     kthrG[gp] = 2.f*chv - 1.00002f;
    }
  } else {
    int tid = ((int)blockIdx.x - GRIDB_)*256 + threadIdx.x;
    if (tid < M_) {
      float th = pix[2*tid], ph = pix[2*tid+1];
      float st = sinf(th);
      float x = st*cosf(ph), y = st*sinf(ph), z = cosf(th);
      r_pix[tid] = make_float4(x, y, z, x*x + y*y + z*z);
      atomicAdd(&cnt[thbkt(th)], 1u);
    }
    int t2 = tid - M_;
    if (t2 >= 0 && t2 < B_*N_) {
      int b = t2 >> 12, n = t2 & (N_-1);
      const float* xb = xxx + b*3*N_;
      float th = xb[n], ph = xb[N_+n], ft = xb[2*N_+n];
      float st = sinf(th);
      r_los[t2] = make_float4(st*cosf(ph), st*sinf(ph), cosf(th), ft);
      atomicAdd(&cnt[256 + b*256 + thbkt(th)], 1u);
    }
    int t3 = tid - M_ - B_*N_;
    if (t3 >= 0 && t3 < B_*H_) gf[t3] = 0.0f;
  }
}

// ---------------- scan ----------------
__global__ __launch_bounds__(256) void scan_vN(
    const unsigned* __restrict__ cnt, int* __restrict__ pstart, int* __restrict__ lstart,
    unsigned* __restrict__ pcur, unsigned* __restrict__ lcur)
{
  __shared__ unsigned buf[256];
  const int t = threadIdx.x;
  for (int arr = 0; arr < 3; ++arr) {
    unsigned v = cnt[arr*256 + t];
    buf[t] = v;
    __syncthreads();
    for (int off = 1; off < 256; off <<= 1) {
      unsigned o = (t >= off) ? buf[t - off] : 0u;
      __syncthreads();
      buf[t] += o;
      __syncthreads();
    }
    unsigned incl = buf[t], excl = incl - v;
    if (arr == 0) {
      pstart[t] = (int)excl; if (t == 255) pstart[256] = (int)incl;
      pcur[t] = excl;
    } else {
      int b = arr - 1;
      lstart[b*257 + t] = (int)excl; if (t == 255) lstart[b*257 + 256] = (int)incl;
      lcur[b*256 + t] = excl;
    }
    __syncthreads();
  }
}

// ---------------- scatter (sldx not needed: sampler keys carry sorted pos) -------------
__global__ __launch_bounds__(256) void scatter_vN(
    const float* __restrict__ xxx, const float* __restrict__ pix,
    const float4* __restrict__ r_pix, const float4* __restrict__ r_los,
    unsigned* __restrict__ pcur, unsigned* __restrict__ lcur,
    float4* __restrict__ spix, int* __restrict__ sjdx,
    float4* __restrict__ slos)
{
  int tid = blockIdx.x * 256 + threadIdx.x;
  if (tid < M_) {
    int bkt = thbkt(pix[2*tid]);
    unsigned pos = atomicAdd(&pcur[bkt], 1u);
    spix[pos] = r_pix[tid];
    sjdx[pos] = tid;
  } else {
    int t2 = tid - M_;
    if (t2 < B_*N_) {
      int b = t2 >> 12, n = t2 & (N_-1);
      int bkt = thbkt(xxx[b*3*N_ + n]);
      unsigned pos = atomicAdd(&lcur[b*256 + bkt], 1u);
      slos[b*N_ + pos] = r_los[t2];
    }
  }
}

// ---------------- sampler vN: vJ structure; OUTPUT IN SORTED SPACE (pooled[b*M + srow]) -------
// GNN runs entirely in sorted space; mean-pool at the end is permutation-invariant.
__global__ __launch_bounds__(512) void sampler_vN(
    const float* __restrict__ pix,
    const float4* __restrict__ spix, const int* __restrict__ sjdx,
    const float4* __restrict__ slos,
    const int* __restrict__ lstart,
    const float* __restrict__ cthrG,
    const float* __restrict__ aw1, const float* __restrict__ ab1,
    const float* __restrict__ aw2, const float* __restrict__ ab2,
    float* __restrict__ pooled)
{
  __shared__ unsigned long long cand[16][SCAP];     // 18 KB
  __shared__ unsigned long long selKey[16][K_];     // 8 KB
  __shared__ unsigned long long bndK[16][BCAP2];    // 6 KB
  __shared__ unsigned hist[16][64];                 // 4 KB   -> 36 KB total, 4 blocks/CU

  const int tid = threadIdx.x, wv = tid >> 6, lane = tid & 63;
  const int b  = blockIdx.y;
  const int srow0 = blockIdx.x*16 + wv*2, srow1 = srow0 + 1;
  const int r0 = wv*2, r1 = r0 + 1;
  const int m0 = sjdx[srow0], m1 = sjdx[srow1];
  const float4 p0 = spix[srow0], p1 = spix[srow1];
  const float thp0 = pix[2*m0], thp1 = pix[2*m1];
  const int g0 = thbkt(thp0), g1 = thbkt(thp1);
  const float th0 = fminf(cthrG[g0], cthrG[g0+1]);
  const float th1 = fminf(cthrG[g1], cthrG[g1+1]);
  const float inv0 = 63.999f / (1.000001f - th0);
  const float inv1 = 63.999f / (1.000001f - th1);
  const float4* sl = slos + b * N_;
  const int* ls = lstart + b * 257;
  const unsigned long long ltm = (1ull << lane) - 1ull;

  // union window bounds
  int jlo, jhi;
  {
    float al0 = acosf(clamp1(th0)), al1 = acosf(clamp1(th1));
    int blo = thbkt(fminf(thp0 - al0, thp1 - al1) - MG_);
    int bhi = thbkt(fmaxf(thp0 + al0, thp1 + al1) + MG_);
    jlo = ls[blo]; jhi = ls[bhi + 1];
  }

  // single pass: dot, predicate, compact candidates of both rows into LDS (pos-keys, no clamp)
  unsigned cnt0 = 0, cnt1 = 0;
  for (int base = jlo; base < jhi; base += 64) {
    int pos = base + lane;
    bool act = pos < jhi;
    float c0 = -2.f, c1 = -2.f;
    if (act) {
      float4 v = sl[pos];
      c0 = v.x*p0.x + v.y*p0.y + v.z*p0.z;
      c1 = v.x*p1.x + v.y*p1.y + v.z*p1.z;
    }
    bool pr0 = c0 > th0, pr1 = c1 > th1;
    unsigned long long mk0 = __ballot(pr0);
    if (mk0) {
      unsigned off = (unsigned)__popcll(mk0 & ltm);
      if (pr0 && cnt0 + off < SCAP) cand[r0][cnt0 + off] = spack(c0, pos);
      cnt0 += (unsigned)__popcll(mk0);
    }
    unsigned long long mk1 = __ballot(pr1);
    if (mk1) {
      unsigned off = (unsigned)__popcll(mk1 & ltm);
      if (pr1 && cnt1 + off < SCAP) cand[r1][cnt1 + off] = spack(c1, pos);
      cnt1 += (unsigned)__popcll(mk1);
    }
  }

  for (int rr = 0; rr < 2; ++rr) {
    const int r = (rr == 0) ? r0 : r1;
    const int srow = (rr == 0) ? srow0 : srow1;
    const float4 p = (rr == 0) ? p0 : p1;
    const float thp = (rr == 0) ? thp0 : thp1;
    const float thg = (rr == 0) ? th0 : th1;
    const float invg = (rr == 0) ? inv0 : inv1;
    unsigned cn = (rr == 0) ? cnt0 : cnt1;
    bool fin = false;

    // fast path: all candidates captured in LDS -> select without touching global
    if (cn >= (unsigned)K_ && cn <= (unsigned)SCAP) {
      hist[r][lane] = 0u;
      for (int i = lane; i < (int)cn; i += 64) {
        float c = key2f((unsigned)(cand[r][i] >> 12));
        atomicAdd(&hist[r][(int)((c - thg) * invg)], 1u);
      }
      unsigned g = hist[r][lane], s = g;
      #pragma unroll
      for (int off = 1; off < 64; off <<= 1) {
        unsigned t2 = (unsigned)__shfl_down((int)s, off);
        s += (lane + off < 64) ? t2 : 0u;
      }
      unsigned snext = s - g;
      unsigned packed = (s >= K_ && snext < K_) ? (((unsigned)(lane+1) << 16) | snext) : 0u;
      #pragma unroll
      for (int off = 32; off; off >>= 1) {
        unsigned o = (unsigned)__shfl_xor((int)packed, off);
        packed = packed > o ? packed : o;
      }
      const int t = (int)(packed >> 16) - 1;
      const unsigned chi = packed & 0xFFFFu;
      const unsigned need = K_ - chi;

      unsigned hiC = 0, bdC = 0;
      for (int i0 = 0; i0 < (int)cn; i0 += 64) {
        int i = i0 + lane;
        bool act = i < (int)cn;
        unsigned long long key = act ? cand[r][i] : 0ull;
        int bin = -1;
        if (act) bin = (int)((key2f((unsigned)(key >> 12)) - thg) * invg);
        bool pHi = act && bin > t, pBd = act && bin == t;
        unsigned long long mH = __ballot(pHi);
        unsigned offH = (unsigned)__popcll(mH & ltm);
        if (pHi && hiC + offH < K_) selKey[r][hiC + offH] = key;
        hiC += (unsigned)__popcll(mH);
        unsigned long long mB = __ballot(pBd);
        unsigned offB = (unsigned)__popcll(mB & ltm);
        if (pBd && bdC + offB < BCAP2) bndK[r][bdC + offB] = key;
        bdC += (unsigned)__popcll(mB);
      }
      if (bdC <= (unsigned)BCAP2) {
        if (lane < (int)bdC) {
          unsigned long long ki = bndK[r][lane];
          int rank = 0;
          for (int j = 0; j < (int)bdC; ++j) rank += (bndK[r][j] > ki) ? 1 : 0;
          if ((unsigned)rank < need) selKey[r][chi + rank] = ki;
        }
        fin = true;
      }
    }

    if (!fin) {
      // slow path (rare: candidate overflow, boundary overflow, or under-count)
      float th = thg;
      float inv = invg;
      int wlo = jlo, whi = jhi;

      if (cn >= (unsigned)K_) {
        // overflow case: rebuild hist over the window at the base threshold
        hist[r][lane] = 0u;
        cn = 0;
        for (int base = wlo; base < whi; base += 64) {
          int pos = base + lane;
          bool act = pos < whi;
          float c = -2.f;
          if (act) {
            float4 v = sl[pos];
            c = clamp1(v.x*p.x + v.y*p.y + v.z*p.z);
          }
          bool pr = c > th;
          if (pr) atomicAdd(&hist[r][(int)((c - th) * inv)], 1u);
          cn += (unsigned)__popcll(__ballot(pr));
        }
      }

      int tries = 0;
      while (cn < K_ && tries < 3) {
        th = 1.f - 1.6f*(1.f - th); ++tries;
        inv = 63.999f / (1.000001f - th);
        float al = acosf(clamp1(th));
        int blo = thbkt(thp - al - MG_), bhi = thbkt(thp + al + MG_);
        wlo = ls[blo]; whi = ls[bhi + 1];
        hist[r][lane] = 0u;
        cn = 0;
        for (int base = wlo; base < whi; base += 64) {
          int pos = base + lane;
          bool act = pos < whi;
          float c = -2.f;
          if (act) {
            float4 v = sl[pos];
            c = clamp1(v.x*p.x + v.y*p.y + v.z*p.z);
          }
          bool pr = c > th;
          if (pr) atomicAdd(&hist[r][(int)((c - th) * inv)], 1u);
          cn += (unsigned)__popcll(__ballot(pr));
        }
      }

      bool fin2 = false;
      if (cn >= K_) {
        unsigned g = hist[r][lane], s = g;
        #pragma unroll
        for (int off = 1; off < 64; off <<= 1) {
          unsigned t2 = (unsigned)__shfl_down((int)s, off);
          s += (lane + off < 64) ? t2 : 0u;
        }
        unsigned snext = s - g;
        unsigned packed = (s >= K_ && snext < K_) ? (((unsigned)(lane+1) << 16) | snext) : 0u;
        #pragma unroll
        for (int off = 32; off; off >>= 1) {
          unsigned o = (unsigned)__shfl_xor((int)packed, off);
          packed = packed > o ? packed : o;
        }
        const int t = (int)(packed >> 16) - 1;
        const unsigned chi = packed & 0xFFFFu;
        const unsigned need = K_ - chi;

        unsigned hiC = 0, bdC = 0;
        for (int base = wlo; base < whi; base += 64) {
          int pos = base + lane;
          bool act = pos < whi;
          float c = -2.f;
          if (act) {
            float4 v = sl[pos];
            c = clamp1(v.x*p.x + v.y*p.y + v.z*p.z);
          }
          int bin = (act && c > th) ? (int)((c - th) * inv) : -1;
          bool pHi = bin > t;
          bool pBd = bin == t;
          unsigned long long mH = __ballot(pHi);
          unsigned offH = (unsigned)__popcll(mH & ltm);
          if (pHi && hiC + offH < K_) selKey[r][hiC + offH] = spack(c, pos);
          hiC += (unsigned)__popcll(mH);
          unsigned long long mB = __ballot(pBd);
          unsigned offB = (unsigned)__popcll(mB & ltm);
          if (pBd && bdC + offB < BCAP2) bndK[r][bdC + offB] = spack(c, pos);
          bdC += (unsigned)__popcll(mB);
        }
        if (bdC <= (unsigned)BCAP2) {
          if (lane < (int)bdC) {
            unsigned long long ki = bndK[r][lane];
            int rank = 0;
            for (int j = 0; j < (int)bdC; ++j) rank += (bndK[r][j] > ki) ? 1 : 0;
            if ((unsigned)rank < need) selKey[r][chi + rank] = ki;
          }
          fin2 = true;
        }
      }

      if (!fin2) {
        // ultimate fallback: exact top-K over the sorted array (pos-keys)
        unsigned long long prev = ~0ull;
        for (int rd = 0; rd < K_; ++rd) {
          unsigned long long best = 0ull;
          for (int i = 0; i < 64; ++i) {
            int pos = lane + 64*i;
            float4 v = sl[pos];
            float c = clamp1(v.x*p.x + v.y*p.y + v.z*p.z);
            unsigned long long k = spack(c, pos);
            if (k < prev && k > best) best = k;
          }
          #pragma unroll
          for (int off = 1; off < 64; off <<= 1) {
            unsigned long long o = shflxor64(best, off);
            best = o > best ? o : best;
          }
          if (lane == 0) selKey[r][rd] = best;
          prev = best;
        }
      }
    }

    // attention MLP + softmax + weighted pool (decode pos; feature from slos.w)
    // OUTPUT IN SORTED SPACE: pooled[b*M + srow]
    {
      unsigned long long key = selKey[r][lane];
      int pos = 4095 - (int)(key & 0xFFFull);
      float c = key2f((unsigned)(key >> 12));
      float xg = sl[pos].w;
      float d  = acosf(clamp1(c));
      float acc = ab2[0];
      for (int s2 = 0; s2 < SH_; ++s2)
        acc += fmaxf(xg*aw1[s2] + d*aw1[SH_+s2] + ab1[s2], 0.f) * aw2[s2];
      float mx = acc;
      #pragma unroll
      for (int off = 32; off; off >>= 1) mx = fmaxf(mx, __shfl_xor(mx, off));
      float e = expf(acc - mx);
      float se = e, sxe = e * xg;
      #pragma unroll
      for (int off = 32; off; off >>= 1) { se += __shfl_xor(se, off); sxe += __shfl_xor(sxe, off); }
      if (lane == 0) pooled[b*M_ + srow] = sxe / se;
    }
  }
}

// ---------------- knn vN (pos-keys; nbr stored in SORTED space: nbr[srow*GK] = pos) ----------
__global__ __launch_bounds__(512) void knn_vN(
    const float* __restrict__ pix,
    const float4* __restrict__ spix, const int* __restrict__ sjdx,
    const int* __restrict__ pstart,
    const float* __restrict__ kthrG, int* __restrict__ nbr)
{
  __shared__ unsigned long long cKey[16][KCAP];

  const int tid = threadIdx.x, wv = tid >> 6, lane = tid & 63;
  const int lr0 = wv*2;
  const int srow0 = blockIdx.x*16 + lr0, srow1 = srow0 + 1;
  const int i0 = sjdx[srow0], i1 = sjdx[srow1];
  const float4 p0 = spix[srow0], p1 = spix[srow1];
  const float thp0 = pix[2*i0], thp1 = pix[2*i1];
  const int g0 = thbkt(thp0), g1 = thbkt(thp1);
  const float t0 = fminf(kthrG[g0], kthrG[g0+1]);
  const float t1 = fminf(kthrG[g1], kthrG[g1+1]);
  const unsigned long long ltm = (1ull << lane) - 1ull;

  unsigned cnt0 = 0, cnt1 = 0;
  {
    float al0 = acosf(clamp1((t0 + 1.00002f)*0.5f));
    float al1 = acosf(clamp1((t1 + 1.00002f)*0.5f));
    int blo = thbkt(fminf(thp0 - al0, thp1 - al1) - MG_);
    int bhi = thbkt(fmaxf(thp0 + al0, thp1 + al1) + MG_);
    int jlo = pstart[blo], jhi = pstart[bhi + 1];
    for (int base = jlo; base < jhi; base += 64) {
      int pos = base + lane;
      bool act = pos < jhi;
      float s0 = -1e30f, s1 = -1e30f;
      if (act) {
        float4 v = spix[pos];
        s0 = 2.f*(p0.x*v.x + p0.y*v.y + p0.z*v.z) - v.w;
        s1 = 2.f*(p1.x*v.x + p1.y*v.y + p1.z*v.z) - v.w;
      }
      bool pr0 = act && (pos != srow0) && (s0 > t0);
      bool pr1 = act && (pos != srow1) && (s1 > t1);
      unsigned long long mk0 = __ballot(pr0);
      if (mk0) {
        unsigned off = (unsigned)__popcll(mk0 & ltm);
        if (pr0 && cnt0 + off < KCAP) cKey[lr0][cnt0 + off] = kpack(s0, pos);
        cnt0 += (unsigned)__popcll(mk0);
      }
      unsigned long long mk1 = __ballot(pr1);
      if (mk1) {
        unsigned off = (unsigned)__popcll(mk1 & ltm);
        if (pr1 && cnt1 + off < KCAP) cKey[lr0+1][cnt1 + off] = kpack(s1, pos);
        cnt1 += (unsigned)__popcll(mk1);
      }
    }
  }

  for (int rr = 0; rr < 2; ++rr) {
    const int lr = lr0 + rr;
    const int srow = (rr == 0) ? srow0 : srow1;
    const float4 pi = (rr == 0) ? p0 : p1;
    const float thp = (rr == 0) ? thp0 : thp1;
    float th = (rr == 0) ? t0 : t1;
    unsigned cn = (rr == 0) ? cnt0 : cnt1;

    int tries = 0;
    while (cn < (unsigned)GK_ && tries < 3) {
      th = 1.6f*th - 0.6f; ++tries;
      float al = acosf(clamp1((th + 1.00002f)*0.5f));
      int blo = thbkt(thp - al - MG_), bhi = thbkt(thp + al + MG_);
      int jlo = pstart[blo], jhi = pstart[bhi + 1];
      cn = 0;
      for (int base = jlo; base < jhi; base += 64) {
        int pos = base + lane;
        bool act = pos < jhi;
        float s = -1e30f;
        if (act) {
          float4 v = spix[pos];
          s = 2.f*(pi.x*v.x + pi.y*v.y + pi.z*v.z) - v.w;
        }
        bool pr = act && (pos != srow) && (s > th);
        unsigned long long mk = __ballot(pr);
        if (mk) {
          unsigned off = (unsigned)__popcll(mk & ltm);
          if (pr && cn + off < KCAP) cKey[lr][cn + off] = kpack(s, pos);
          cn += (unsigned)__popcll(mk);
        }
      }
    }

    if (cn >= (unsigned)GK_ && cn <= (unsigned)KCAP) {
      unsigned long long pk[2];
      #pragma unroll
      for (int t2 = 0; t2 < 2; ++t2) {
        int idx = lane + 64*t2;
        pk[t2] = (idx < (int)cn) ? cKey[lr][idx] : 0ull;
      }
      for (int round = 0; round < GK_; ++round) {
        unsigned long long loc = pk[0]; int lt = 0;
        if (pk[1] > loc) { loc = pk[1]; lt = 1; }
        unsigned long long best = loc;
        #pragma unroll
        for (int off = 1; off < 64; off <<= 1) {
          unsigned long long o = shflxor64(best, off);
          best = o > best ? o : best;
        }
        if (loc == best) pk[lt] = 0ull;
        if (lane == round) nbr[srow*GK_ + round] = 16383 - (int)(best & 16383ull);
      }
    } else {
      unsigned long long prev = ~0ull;
      for (int rd = 0; rd < GK_; ++rd) {
        unsigned long long best = 0ull;
        for (int pos = lane; pos < M_; pos += 64) {
          float4 v = spix[pos];
          float s = 2.f*(pi.x*v.x + pi.y*v.y + pi.z*v.z) - v.w;
          if (pos != srow) {
            unsigned long long k = kpack(s, pos);
            if (k < prev && k > best) best = k;
          }
        }
        #pragma unroll
        for (int off = 1; off < 64; off <<= 1) {
          unsigned long long o = shflxor64(best, off);
          best = o > best ? o : best;
        }
        if (lane == rd) nbr[srow*GK_ + rd] = 16383 - (int)(best & 16383ull);
        prev = best;
      }
    }
  }
}

// ---------------- GNN layer 1 fused with proj (sorted space; readlane matmul) ----------------
__global__ __launch_bounds__(256) void gnn1f_vN(
    const float* __restrict__ pooled, float* __restrict__ hout, const int* __restrict__ nbr,
    const float* __restrict__ pw, const float* __restrict__ pb,
    const float* __restrict__ relw, const float* __restrict__ relb,
    const float* __restrict__ rootw)
{
  __shared__ float wrel[H_*H_], wroot[H_*H_];
  const int tid = threadIdx.x;
  {
    const float4* rw4 = (const float4*)relw;
    const float4* ow4 = (const float4*)rootw;
    float4* wr4 = (float4*)wrel;
    float4* wo4 = (float4*)wroot;
    #pragma unroll
    for (int q = 0; q < 4; ++q) {
      int idx = tid + 256*q;
      wr4[idx] = rw4[idx];
      wo4[idx] = ow4[idx];
    }
  }
  __syncthreads();

  const int lane = tid & 63;
  const int wave = tid >> 6;
  const int b = blockIdx.y;
  const int m0 = blockIdx.x * 16 + wave * 4;
  const float* pldb = pooled + (size_t)b * M_;
  const float pwl = pw[lane], pbl = pb[lane], rbl = relb[lane];

  float h[4], agg[4], acc[4];
  #pragma unroll
  for (int t = 0; t < 4; ++t) {
    int m = m0 + t;
    float ps = pldb[m];
    h[t] = fmaxf(ps*pwl + pbl, 0.f);
    float a = 0.f;
    #pragma unroll
    for (int k = 0; k < GK_; ++k) {
      int nb = nbr[m*GK_ + k];
      nb = nb < 0 ? 0 : (nb >= M_ ? M_-1 : nb);
      float pn = pldb[nb];
      a += fmaxf(pn*pwl + pbl, 0.f);
    }
    agg[t] = a;
    acc[t] = rbl;
  }
  #pragma unroll
  for (int c = 0; c < H_; ++c) {
    float wr = wrel[c*H_ + lane], wo = wroot[c*H_ + lane];
    #pragma unroll
    for (int t = 0; t < 4; ++t)
      acc[t] += rdlane(agg[t], c) * wr + rdlane(h[t], c) * wo;
  }
  #pragma unroll
  for (int t = 0; t < 4; ++t)
    hout[((size_t)b*M_ + m0 + t)*H_ + lane] = fmaxf(acc[t], 0.f);
}

// ---------------- GNN layer (generic, sorted space; readlane matmul) ----------------
__global__ __launch_bounds__(256) void gnn_vN(
    const float* __restrict__ hin, float* __restrict__ hout, const int* __restrict__ nbr,
    const float* __restrict__ relw, const float* __restrict__ relb,
    const float* __restrict__ rootw)
{
  __shared__ float wrel[H_*H_], wroot[H_*H_];
  const int tid = threadIdx.x;
  {
    const float4* rw4 = (const float4*)relw;
    const float4* ow4 = (const float4*)rootw;
    float4* wr4 = (float4*)wrel;
    float4* wo4 = (float4*)wroot;
    #pragma unroll
    for (int q = 0; q < 4; ++q) {
      int idx = tid + 256*q;
      wr4[idx] = rw4[idx];
      wo4[idx] = ow4[idx];
    }
  }
  __syncthreads();

  const int lane = tid & 63;
  const int wave = tid >> 6;
  const int b = blockIdx.y;
  const int m0 = blockIdx.x * 16 + wave * 4;
  const float* hb = hin + (size_t)b * M_ * H_;
  const float rbl = relb[lane];

  float h[4], agg[4], acc[4];
  #pragma unroll
  for (int t = 0; t < 4; ++t) {
    int m = m0 + t;
    h[t] = hb[m*H_ + lane];
    float a = 0.f;
    #pragma unroll
    for (int k = 0; k < GK_; ++k) {
      int nb = nbr[m*GK_ + k];
      nb = nb < 0 ? 0 : (nb >= M_ ? M_-1 : nb);
      a += hb[nb*H_ + lane];
    }
    agg[t] = a;
    acc[t] = rbl;
  }
  #pragma unroll
  for (int c = 0; c < H_; ++c) {
    float wr = wrel[c*H_ + lane], wo = wroot[c*H_ + lane];
    #pragma unroll
    for (int t = 0; t < 4; ++t)
      acc[t] += rdlane(agg[t], c) * wr + rdlane(h[t], c) * wo;
  }
  #pragma unroll
  for (int t = 0; t < 4; ++t)
    hout[((size_t)b*M_ + m0 + t)*H_ + lane] = fmaxf(acc[t], 0.f);
}

// ---------------- GNN layer 3 + fused global-mean reduce (sorted space; mean is perm-invariant)
__global__ __launch_bounds__(256) void gnn3r_vN(
    const float* __restrict__ hin, float* __restrict__ gf, const int* __restrict__ nbr,
    const float* __restrict__ relw, const float* __restrict__ relb,
    const float* __restrict__ rootw)
{
  __shared__ float wrel[H_*H_], wroot[H_*H_];
  __shared__ float gacc[H_];
  const int tid = threadIdx.x;
  {
    const float4* rw4 = (const float4*)relw;
    const float4* ow4 = (const float4*)rootw;
    float4* wr4 = (float4*)wrel;
    float4* wo4 = (float4*)wroot;
    #pragma unroll
    for (int q = 0; q < 4; ++q) {
      int idx = tid + 256*q;
      wr4[idx] = rw4[idx];
      wo4[idx] = ow4[idx];
    }
  }
  if (tid < H_) gacc[tid] = 0.f;
  __syncthreads();

  const int lane = tid & 63;
  const int wave = tid >> 6;
  const int b = blockIdx.y;
  const int m0 = blockIdx.x * 16 + wave * 4;
  const float* hb = hin + (size_t)b * M_ * H_;
  const float rbl = relb[lane];

  float h[4], agg[4], acc[4];
  #pragma unroll
  for (int t = 0; t < 4; ++t) {
    int m = m0 + t;
    h[t] = hb[m*H_ + lane];
    float a = 0.f;
    #pragma unroll
    for (int k = 0; k < GK_; ++k) {
      int nb = nbr[m*GK_ + k];
      nb = nb < 0 ? 0 : (nb >= M_ ? M_-1 : nb);
      a += hb[nb*H_ + lane];
    }
    agg[t] = a;
    acc[t] = rbl;
  }
  #pragma unroll
  for (int c = 0; c < H_; ++c) {
    float wr = wrel[c*H_ + lane], wo = wroot[c*H_ + lane];
    #pragma unroll
    for (int t = 0; t < 4; ++t)
      acc[t] += rdlane(agg[t], c) * wr + rdlane(h[t], c) * wo;
  }
  float ps = fmaxf(acc[0], 0.f) + fmaxf(acc[1], 0.f) + fmaxf(acc[2], 0.f) + fmaxf(acc[3], 0.f);
  atomicAdd(&gacc[lane], ps);
  __syncthreads();
  if (tid < H_) atomicAdd(&gf[b*H_ + tid], gacc[tid]);
}

// ---------------- head ----------------
__global__ __launch_bounds__(256) void head_vN(
    const float* __restrict__ gf, const float* __restrict__ w1,
    const float* __restrict__ b1, const float* __restrict__ w2,
    const float* __restrict__ b2, float* __restrict__ out)
{
  __shared__ float gfm[B_][H_], hid[B_][H_];
  const int tid = threadIdx.x;
  if (tid < B_*H_) gfm[tid >> 6][tid & 63] = gf[tid] * (1.f / (float)M_);
  __syncthreads();
  if (tid < B_*H_) {
    int b = tid >> 6, j = tid & 63;
    float acc = b1[j];
    for (int c = 0; c < H_; ++c) acc += gfm[b][c] * w1[c*H_ + j];
    hid[b][j] = fmaxf(acc, 0.f);
  }
  __syncthreads();
  for (int t = tid; t < B_*NC_; t += 256) {
    int b = t / NC_, o = t - b*NC_;
    float acc = b2[o];
    for (int j = 0; j < H_; ++j) acc += hid[b][j] * w2[j*NC_ + o];
    out[t] = acc;
  }
}

extern "C" void kernel_launch(void* const* d_in, const int* in_sizes, int n_in,
                              void* d_out, int out_size, void* d_ws, size_t ws_size,
                              hipStream_t stream)
{
  float* out = (float*)d_out;

  const size_t need = (size_t)M_*16 + (size_t)B_*N_*16 + (size_t)B_*M_*4
                    + (size_t)M_*GK_*4 + 2*(size_t)B_*M_*H_*4 + (size_t)B_*H_*4;
  bool ok_ws = ws_size >= need;
  bool ok_in = (n_in == 15) && (out_size == B_*NC_)
            && in_sizes[0] == B_*3*N_ && in_sizes[1] == M_*2
            && in_sizes[2] == 2*SH_ && in_sizes[5] == 1
            && in_sizes[8] == 3*H_*H_ && in_sizes[13] == H_*NC_;
  if (!ok_ws || !ok_in) {
    sentinel_vN<<<(out_size + 255)/256, 256, 0, stream>>>(out, out_size, ok_in ? 42.f : 43.f);
    return;
  }

  const float* xxx    = (const float*)d_in[0];
  const float* pix    = (const float*)d_in[1];
  const float* att_w1 = (const float*)d_in[2];
  const float* att_b1 = (const float*)d_in[3];
  const float* att_w2 = (const float*)d_in[4];
  const float* att_b2 = (const float*)d_in[5];
  const float* proj_w = (const float*)d_in[6];
  const float* proj_b = (const float*)d_in[7];
  const float* rel_w  = (const float*)d_in[8];
  const float* rel_b  = (const float*)d_in[9];
  const float* root_w = (const float*)d_in[10];
  const float* out_w1 = (const float*)d_in[11];
  const float* out_b1 = (const float*)d_in[12];
  const float* out_w2 = (const float*)d_in[13];
  const float* out_b2 = (const float*)d_in[14];

  char* w = (char*)d_ws;
  float4* r_pix = (float4*)w;  w += (size_t)M_ * 16;
  float4* r_los = (float4*)w;  w += (size_t)B_ * N_ * 16;
  float*  pooled = (float*)w;  w += (size_t)B_ * M_ * 4;
  int*    nbr = (int*)w;       w += (size_t)M_ * GK_ * 4;
  float*  h0 = (float*)w;      w += (size_t)B_ * M_ * H_ * 4;
  float*  h1 = (float*)w;      w += (size_t)B_ * M_ * H_ * 4;
  float*  gf = (float*)w;      w += (size_t)B_ * H_ * 4;

  // sort/threshold scratch aliases h0 (dead until gnn layer 2 writes it)
  float*  kthrG = h0;                                  // 257 grid thresholds (knn)
  float*  cthrG = h0 + 512;                            // 257 grid thresholds (sampler)
  float4* spix = (float4*)(h0 + 2*M_);                 // M float4
  int*    sjdx = (int*)(h0 + 6*M_);                    // M
  float4* slos = (float4*)(h0 + 7*M_);                 // B*N float4
  unsigned* cnt = (unsigned*)(h0 + 7*M_ + 5*B_*N_);    // 768
  int*    pstart = (int*)(cnt + 768);                  // 257
  int*    lstart = pstart + 257;                       // 2*257
  unsigned* pcur = (unsigned*)(lstart + 514);          // 256
  unsigned* lcur = pcur + 256;                         // 512

  hipMemsetAsync(cnt, 0, 768*sizeof(unsigned), stream);
  prep_vN<<<GRIDB_ + PREPB_, 256, 0, stream>>>(xxx, pix, r_pix, r_los, gf, kthrG, cthrG, cnt);
  scan_vN<<<1, 256, 0, stream>>>(cnt, pstart, lstart, pcur, lcur);
  scatter_vN<<<(M_ + B_*N_ + 255)/256, 256, 0, stream>>>(xxx, pix, r_pix, r_los, pcur, lcur,
                                                         spix, sjdx, slos);
  sampler_vN<<<dim3(M_/16, B_), 512, 0, stream>>>(pix, spix, sjdx, slos, lstart,
                                                  cthrG, att_w1, att_b1, att_w2, att_b2, pooled);
  knn_vN<<<M_/16, 512, 0, stream>>>(pix, spix, sjdx, pstart, kthrG, nbr);
  gnn1f_vN<<<dim3(M_/16, B_), 256, 0, stream>>>(pooled, h1, nbr, proj_w, proj_b,
                                                rel_w + 0*H_*H_, rel_b + 0*H_, root_w + 0*H_*H_);
  gnn_vN<<<dim3(M_/16, B_), 256, 0, stream>>>(h1, h0, nbr, rel_w + 1*H_*H_, rel_b + 1*H_, root_w + 1*H_*H_);
  gnn3r_vN<<<dim3(M_/16, B_), 256, 0, stream>>>(h0, gf, nbr, rel_w + 2*H_*H_, rel_b + 2*H_, root_w + 2*H_*H_);
  head_vN<<<1, 256, 0, stream>>>(gf, out_w1, out_b1, out_w2, out_b2, out);
}

// Round 10
// 229.832 us; speedup vs baseline: 1.1451x; 1.0227x over previous
//
#include <hip/hip_runtime.h>
#include <hip/hip_bf16.h>

#define B_ 2
#define N_ 4096
#define M_ 12288
#define K_ 64
#define SH_ 32
#define H_ 64
#define GK_ 8
#define NC_ 200

#define KCAP 128       // knn candidate cap (E=40, +13 sigma)
#define BCAP2 48       // sampler boundary cap
#define SCAP 144       // sampler stored-candidate cap (E=96, +4.9 sigma; overflow -> slow path)
#define MG_ 0.01f      // theta-window safety margin (rad)
#define C256_ 81.48733086f   // 256/pi

// GNN tiling: 32 rows/block, 8 rows/wave; grid M_/32 = 384 blocks (div by 8 for XCD swizzle)
#define GROWS 32
#define GWROWS 8
#define GBLK (M_/GROWS)       // 384
#define GCHUNK (GBLK/8)       // 48 blocks per XCD chunk

static __device__ __forceinline__ unsigned f2key(float f) {
  unsigned b = __float_as_uint(f);
  return (b & 0x80000000u) ? ~b : (b | 0x80000000u);
}
static __device__ __forceinline__ float key2f(unsigned u) {
  unsigned b = (u & 0x80000000u) ? (u & 0x7fffffffu) : ~u;
  return __uint_as_float(b);
}
static __device__ __forceinline__ unsigned long long shflxor64(unsigned long long x, int m) {
  unsigned lo = (unsigned)x, hi = (unsigned)(x >> 32);
  lo = (unsigned)__shfl_xor((int)lo, m);
  hi = (unsigned)__shfl_xor((int)hi, m);
  return ((unsigned long long)hi << 32) | lo;
}
// keys carry SORTED positions (known from loop counter; no index load in scans)
static __device__ __forceinline__ unsigned long long kpack(float s, int pos) {
  return ((unsigned long long)f2key(s) << 14) | (unsigned)(16383 - pos);
}
static __device__ __forceinline__ unsigned long long spack(float c, int pos) {
  return ((unsigned long long)f2key(c) << 12) | (unsigned)(4095 - pos);
}
static __device__ __forceinline__ int thbkt(float th) {
  int b = (int)(th * C256_);
  return b < 0 ? 0 : (b > 255 ? 255 : b);
}
static __device__ __forceinline__ float clamp1(float x) { return fminf(1.f, fmaxf(-1.f, x)); }
static __device__ __forceinline__ float rdlane(float v, int c) {
  return __uint_as_float((unsigned)__builtin_amdgcn_readlane((int)__float_as_uint(v), c));
}

// ---------------- sentinel ----------------
__global__ __launch_bounds__(256) void sentinel_vO(float* out, int n, float val) {
  int t = blockIdx.x * 256 + threadIdx.x;
  if (t < n) out[t] = val;
}

// ---------------- prep + GRID thresholds (257-pt theta grid) + theta-band hist ----------------
#define GRIDB_ 129     // 129 blocks x 4 waves = 516 jobs >= 2*257
#define PREPN_ (M_ + B_*N_ + B_*H_)
#define PREPB_ ((PREPN_ + 255)/256)

__global__ __launch_bounds__(256) void prep_vO(
    const float* __restrict__ xxx, const float* __restrict__ pix,
    float4* __restrict__ r_pix, float4* __restrict__ r_los, float* __restrict__ gf,
    float* __restrict__ kthrG, float* __restrict__ cthrG, unsigned* __restrict__ cnt)
{
  const float PI = 3.14159265358979f;
  if ((int)blockIdx.x < GRIDB_) {
    int gid  = blockIdx.x*4 + (threadIdx.x >> 6);
    if (gid >= 514) return;
    int lane = threadIdx.x & 63;
    int tgt  = (gid >= 257) ? 1 : 0;
    int gp   = gid - tgt*257;
    float thp = (float)gp * (PI/256.f);
    float cp = cosf(thp), sp = fmaxf(sinf(thp), 1e-6f);
    float thq = ((float)lane + 0.5f) * (PI/64.f);
    float sq = sinf(thq), cq = cosf(thq);
    float rinv = 1.0f / (sq * sp);
    // E targets: sampler 96 of N, knn 40 of M (top-K invariant to threshold while count>=K;
    // retry ladder covers the ~5e-4 under-count tail)
    float At = tgt ? (2.f*PI*PI*96.f/(float)N_) : (2.f*PI*PI*40.f/(float)M_);
    float lo = 1e-3f, hi = 3.1414f;
    for (int it = 0; it < 12; ++it) {
      float al = 0.5f*(lo + hi);
      float ca = cosf(al);
      float arg = clamp1((ca - cq*cp) * rinv);
      float ax = fabsf(arg);
      float ac = sqrtf(fmaxf(0.f, 1.f - ax)) *
                 fmaf(ax, fmaf(ax, fmaf(ax, -0.0187293f, 0.0742610f), -0.2121144f), 1.5707288f);
      ac = (arg < 0.f) ? (PI - ac) : ac;
      float S = ac;
      #pragma unroll
      for (int off = 32; off; off >>= 1) S += __shfl_xor(S, off);
      float A = 2.f * S * (PI/64.f);
      if (A < At) lo = al; else hi = al;
    }
    if (lane == 0) {
      float chv = cosf(hi);
      if (tgt) cthrG[gp] = chv - 1e-5f;
      else     kthrG[gp] = 2.f*chv - 1.00002f;
    }
  } else {
    int tid = ((int)blockIdx.x - GRIDB_)*256 + threadIdx.x;
    if (tid < M_) {
      float th = pix[2*tid], ph = pix[2*tid+1];
      float st = sinf(th);
      float x = st*cosf(ph), y = st*sinf(ph), z = cosf(th);
      r_pix[tid] = make_float4(x, y, z, x*x + y*y + z*z);
      atomicAdd(&cnt[thbkt(th)], 1u);
    }
    int t2 = tid - M_;
    if (t2 >= 0 && t2 < B_*N_) {
      int b = t2 >> 12, n = t2 & (N_-1);
      const float* xb = xxx + b*3*N_;
      float th = xb[n], ph = xb[N_+n], ft = xb[2*N_+n];
      float st = sinf(th);
      r_los[t2] = make_float4(st*cosf(ph), st*sinf(ph), cosf(th), ft);
      atomicAdd(&cnt[256 + b*256 + thbkt(th)], 1u);
    }
    int t3 = tid - M_ - B_*N_;
    if (t3 >= 0 && t3 < B_*H_) gf[t3] = 0.0f;
  }
}

// ---------------- scan ----------------
__global__ __launch_bounds__(256) void scan_vO(
    const unsigned* __restrict__ cnt, int* __restrict__ pstart, int* __restrict__ lstart,
    unsigned* __restrict__ pcur, unsigned* __restrict__ lcur)
{
  __shared__ unsigned buf[256];
  const int t = threadIdx.x;
  for (int arr = 0; arr < 3; ++arr) {
    unsigned v = cnt[arr*256 + t];
    buf[t] = v;
    __syncthreads();
    for (int off = 1; off < 256; off <<= 1) {
      unsigned o = (t >= off) ? buf[t - off] : 0u;
      __syncthreads();
      buf[t] += o;
      __syncthreads();
    }
    unsigned incl = buf[t], excl = incl - v;
    if (arr == 0) {
      pstart[t] = (int)excl; if (t == 255) pstart[256] = (int)incl;
      pcur[t] = excl;
    } else {
      int b = arr - 1;
      lstart[b*257 + t] = (int)excl; if (t == 255) lstart[b*257 + 256] = (int)incl;
      lcur[b*256 + t] = excl;
    }
    __syncthreads();
  }
}

// ---------------- scatter (sldx not needed: sampler keys carry sorted pos) -------------
__global__ __launch_bounds__(256) void scatter_vO(
    const float* __restrict__ xxx, const float* __restrict__ pix,
    const float4* __restrict__ r_pix, const float4* __restrict__ r_los,
    unsigned* __restrict__ pcur, unsigned* __restrict__ lcur,
    float4* __restrict__ spix, int* __restrict__ sjdx,
    float4* __restrict__ slos)
{
  int tid = blockIdx.x * 256 + threadIdx.x;
  if (tid < M_) {
    int bkt = thbkt(pix[2*tid]);
    unsigned pos = atomicAdd(&pcur[bkt], 1u);
    spix[pos] = r_pix[tid];
    sjdx[pos] = tid;
  } else {
    int t2 = tid - M_;
    if (t2 < B_*N_) {
      int b = t2 >> 12, n = t2 & (N_-1);
      int bkt = thbkt(xxx[b*3*N_ + n]);
      unsigned pos = atomicAdd(&lcur[b*256 + bkt], 1u);
      slos[b*N_ + pos] = r_los[t2];
    }
  }
}

// ---------------- sampler vO: vJ structure; OUTPUT IN SORTED SPACE (pooled[b*M + srow]) -------
__global__ __launch_bounds__(512) void sampler_vO(
    const float* __restrict__ pix,
    const float4* __restrict__ spix, const int* __restrict__ sjdx,
    const float4* __restrict__ slos,
    const int* __restrict__ lstart,
    const float* __restrict__ cthrG,
    const float* __restrict__ aw1, const float* __restrict__ ab1,
    const float* __restrict__ aw2, const float* __restrict__ ab2,
    float* __restrict__ pooled)
{
  __shared__ unsigned long long cand[16][SCAP];     // 18 KB
  __shared__ unsigned long long selKey[16][K_];     // 8 KB
  __shared__ unsigned long long bndK[16][BCAP2];    // 6 KB
  __shared__ unsigned hist[16][64];                 // 4 KB   -> 36 KB total, 4 blocks/CU

  const int tid = threadIdx.x, wv = tid >> 6, lane = tid & 63;
  const int b  = blockIdx.y;
  const int srow0 = blockIdx.x*16 + wv*2, srow1 = srow0 + 1;
  const int r0 = wv*2, r1 = r0 + 1;
  const int m0 = sjdx[srow0], m1 = sjdx[srow1];
  const float4 p0 = spix[srow0], p1 = spix[srow1];
  const float thp0 = pix[2*m0], thp1 = pix[2*m1];
  const int g0 = thbkt(thp0), g1 = thbkt(thp1);
  const float th0 = fminf(cthrG[g0], cthrG[g0+1]);
  const float th1 = fminf(cthrG[g1], cthrG[g1+1]);
  const float inv0 = 63.999f / (1.000001f - th0);
  const float inv1 = 63.999f / (1.000001f - th1);
  const float4* sl = slos + b * N_;
  const int* ls = lstart + b * 257;
  const unsigned long long ltm = (1ull << lane) - 1ull;

  // union window bounds
  int jlo, jhi;
  {
    float al0 = acosf(clamp1(th0)), al1 = acosf(clamp1(th1));
    int blo = thbkt(fminf(thp0 - al0, thp1 - al1) - MG_);
    int bhi = thbkt(fmaxf(thp0 + al0, thp1 + al1) + MG_);
    jlo = ls[blo]; jhi = ls[bhi + 1];
  }

  // single pass: dot, predicate, compact candidates of both rows into LDS (pos-keys, no clamp)
  unsigned cnt0 = 0, cnt1 = 0;
  for (int base = jlo; base < jhi; base += 64) {
    int pos = base + lane;
    bool act = pos < jhi;
    float c0 = -2.f, c1 = -2.f;
    if (act) {
      float4 v = sl[pos];
      c0 = v.x*p0.x + v.y*p0.y + v.z*p0.z;
      c1 = v.x*p1.x + v.y*p1.y + v.z*p1.z;
    }
    bool pr0 = c0 > th0, pr1 = c1 > th1;
    unsigned long long mk0 = __ballot(pr0);
    if (mk0) {
      unsigned off = (unsigned)__popcll(mk0 & ltm);
      if (pr0 && cnt0 + off < SCAP) cand[r0][cnt0 + off] = spack(c0, pos);
      cnt0 += (unsigned)__popcll(mk0);
    }
    unsigned long long mk1 = __ballot(pr1);
    if (mk1) {
      unsigned off = (unsigned)__popcll(mk1 & ltm);
      if (pr1 && cnt1 + off < SCAP) cand[r1][cnt1 + off] = spack(c1, pos);
      cnt1 += (unsigned)__popcll(mk1);
    }
  }

  for (int rr = 0; rr < 2; ++rr) {
    const int r = (rr == 0) ? r0 : r1;
    const int srow = (rr == 0) ? srow0 : srow1;
    const float4 p = (rr == 0) ? p0 : p1;
    const float thp = (rr == 0) ? thp0 : thp1;
    const float thg = (rr == 0) ? th0 : th1;
    const float invg = (rr == 0) ? inv0 : inv1;
    unsigned cn = (rr == 0) ? cnt0 : cnt1;
    bool fin = false;

    // fast path: all candidates captured in LDS -> select without touching global
    if (cn >= (unsigned)K_ && cn <= (unsigned)SCAP) {
      hist[r][lane] = 0u;
      for (int i = lane; i < (int)cn; i += 64) {
        float c = key2f((unsigned)(cand[r][i] >> 12));
        atomicAdd(&hist[r][(int)((c - thg) * invg)], 1u);
      }
      unsigned g = hist[r][lane], s = g;
      #pragma unroll
      for (int off = 1; off < 64; off <<= 1) {
        unsigned t2 = (unsigned)__shfl_down((int)s, off);
        s += (lane + off < 64) ? t2 : 0u;
      }
      unsigned snext = s - g;
      unsigned packed = (s >= K_ && snext < K_) ? (((unsigned)(lane+1) << 16) | snext) : 0u;
      #pragma unroll
      for (int off = 32; off; off >>= 1) {
        unsigned o = (unsigned)__shfl_xor((int)packed, off);
        packed = packed > o ? packed : o;
      }
      const int t = (int)(packed >> 16) - 1;
      const unsigned chi = packed & 0xFFFFu;
      const unsigned need = K_ - chi;

      unsigned hiC = 0, bdC = 0;
      for (int i0 = 0; i0 < (int)cn; i0 += 64) {
        int i = i0 + lane;
        bool act = i < (int)cn;
        unsigned long long key = act ? cand[r][i] : 0ull;
        int bin = -1;
        if (act) bin = (int)((key2f((unsigned)(key >> 12)) - thg) * invg);
        bool pHi = act && bin > t, pBd = act && bin == t;
        unsigned long long mH = __ballot(pHi);
        unsigned offH = (unsigned)__popcll(mH & ltm);
        if (pHi && hiC + offH < K_) selKey[r][hiC + offH] = key;
        hiC += (unsigned)__popcll(mH);
        unsigned long long mB = __ballot(pBd);
        unsigned offB = (unsigned)__popcll(mB & ltm);
        if (pBd && bdC + offB < BCAP2) bndK[r][bdC + offB] = key;
        bdC += (unsigned)__popcll(mB);
      }
      if (bdC <= (unsigned)BCAP2) {
        if (lane < (int)bdC) {
          unsigned long long ki = bndK[r][lane];
          int rank = 0;
          for (int j = 0; j < (int)bdC; ++j) rank += (bndK[r][j] > ki) ? 1 : 0;
          if ((unsigned)rank < need) selKey[r][chi + rank] = ki;
        }
        fin = true;
      }
    }

    if (!fin) {
      // slow path (rare: candidate overflow, boundary overflow, or under-count)
      float th = thg;
      float inv = invg;
      int wlo = jlo, whi = jhi;

      if (cn >= (unsigned)K_) {
        // overflow case: rebuild hist over the window at the base threshold
        hist[r][lane] = 0u;
        cn = 0;
        for (int base = wlo; base < whi; base += 64) {
          int pos = base + lane;
          bool act = pos < whi;
          float c = -2.f;
          if (act) {
            float4 v = sl[pos];
            c = clamp1(v.x*p.x + v.y*p.y + v.z*p.z);
          }
          bool pr = c > th;
          if (pr) atomicAdd(&hist[r][(int)((c - th) * inv)], 1u);
          cn += (unsigned)__popcll(__ballot(pr));
        }
      }

      int tries = 0;
      while (cn < K_ && tries < 3) {
        th = 1.f - 1.6f*(1.f - th); ++tries;
        inv = 63.999f / (1.000001f - th);
        float al = acosf(clamp1(th));
        int blo = thbkt(thp - al - MG_), bhi = thbkt(thp + al + MG_);
        wlo = ls[blo]; whi = ls[bhi + 1];
        hist[r][lane] = 0u;
        cn = 0;
        for (int base = wlo; base < whi; base += 64) {
          int pos = base + lane;
          bool act = pos < whi;
          float c = -2.f;
          if (act) {
            float4 v = sl[pos];
            c = clamp1(v.x*p.x + v.y*p.y + v.z*p.z);
          }
          bool pr = c > th;
          if (pr) atomicAdd(&hist[r][(int)((c - th) * inv)], 1u);
          cn += (unsigned)__popcll(__ballot(pr));
        }
      }

      bool fin2 = false;
      if (cn >= K_) {
        unsigned g = hist[r][lane], s = g;
        #pragma unroll
        for (int off = 1; off < 64; off <<= 1) {
          unsigned t2 = (unsigned)__shfl_down((int)s, off);
          s += (lane + off < 64) ? t2 : 0u;
        }
        unsigned snext = s - g;
        unsigned packed = (s >= K_ && snext < K_) ? (((unsigned)(lane+1) << 16) | snext) : 0u;
        #pragma unroll
        for (int off = 32; off; off >>= 1) {
          unsigned o = (unsigned)__shfl_xor((int)packed, off);
          packed = packed > o ? packed : o;
        }
        const int t = (int)(packed >> 16) - 1;
        const unsigned chi = packed & 0xFFFFu;
        const unsigned need = K_ - chi;

        unsigned hiC = 0, bdC = 0;
        for (int base = wlo; base < whi; base += 64) {
          int pos = base + lane;
          bool act = pos < whi;
          float c = -2.f;
          if (act) {
            float4 v = sl[pos];
            c = clamp1(v.x*p.x + v.y*p.y + v.z*p.z);
          }
          int bin = (act && c > th) ? (int)((c - th) * inv) : -1;
          bool pHi = bin > t;
          bool pBd = bin == t;
          unsigned long long mH = __ballot(pHi);
          unsigned offH = (unsigned)__popcll(mH & ltm);
          if (pHi && hiC + offH < K_) selKey[r][hiC + offH] = spack(c, pos);
          hiC += (unsigned)__popcll(mH);
          unsigned long long mB = __ballot(pBd);
          unsigned offB = (unsigned)__popcll(mB & ltm);
          if (pBd && bdC + offB < BCAP2) bndK[r][bdC + offB] = spack(c, pos);
          bdC += (unsigned)__popcll(mB);
        }
        if (bdC <= (unsigned)BCAP2) {
          if (lane < (int)bdC) {
            unsigned long long ki = bndK[r][lane];
            int rank = 0;
            for (int j = 0; j < (int)bdC; ++j) rank += (bndK[r][j] > ki) ? 1 : 0;
            if ((unsigned)rank < need) selKey[r][chi + rank] = ki;
          }
          fin2 = true;
        }
      }

      if (!fin2) {
        // ultimate fallback: exact top-K over the sorted array (pos-keys)
        unsigned long long prev = ~0ull;
        for (int rd = 0; rd < K_; ++rd) {
          unsigned long long best = 0ull;
          for (int i = 0; i < 64; ++i) {
            int pos = lane + 64*i;
            float4 v = sl[pos];
            float c = clamp1(v.x*p.x + v.y*p.y + v.z*p.z);
            unsigned long long k = spack(c, pos);
            if (k < prev && k > best) best = k;
          }
          #pragma unroll
          for (int off = 1; off < 64; off <<= 1) {
            unsigned long long o = shflxor64(best, off);
            best = o > best ? o : best;
          }
          if (lane == 0) selKey[r][rd] = best;
          prev = best;
        }
      }
    }

    // attention MLP + softmax + weighted pool; OUTPUT IN SORTED SPACE: pooled[b*M + srow]
    {
      unsigned long long key = selKey[r][lane];
      int pos = 4095 - (int)(key & 0xFFFull);
      float c = key2f((unsigned)(key >> 12));
      float xg = sl[pos].w;
      float d  = acosf(clamp1(c));
      float acc = ab2[0];
      for (int s2 = 0; s2 < SH_; ++s2)
        acc += fmaxf(xg*aw1[s2] + d*aw1[SH_+s2] + ab1[s2], 0.f) * aw2[s2];
      float mx = acc;
      #pragma unroll
      for (int off = 32; off; off >>= 1) mx = fmaxf(mx, __shfl_xor(mx, off));
      float e = expf(acc - mx);
      float se = e, sxe = e * xg;
      #pragma unroll
      for (int off = 32; off; off >>= 1) { se += __shfl_xor(se, off); sxe += __shfl_xor(sxe, off); }
      if (lane == 0) pooled[b*M_ + srow] = sxe / se;
    }
  }
}

// ---------------- knn vO (pos-keys; nbr stored in SORTED space: nbr[srow*GK] = pos) ----------
__global__ __launch_bounds__(512) void knn_vO(
    const float* __restrict__ pix,
    const float4* __restrict__ spix, const int* __restrict__ sjdx,
    const int* __restrict__ pstart,
    const float* __restrict__ kthrG, int* __restrict__ nbr)
{
  __shared__ unsigned long long cKey[16][KCAP];

  const int tid = threadIdx.x, wv = tid >> 6, lane = tid & 63;
  const int lr0 = wv*2;
  const int srow0 = blockIdx.x*16 + lr0, srow1 = srow0 + 1;
  const int i0 = sjdx[srow0], i1 = sjdx[srow1];
  const float4 p0 = spix[srow0], p1 = spix[srow1];
  const float thp0 = pix[2*i0], thp1 = pix[2*i1];
  const int g0 = thbkt(thp0), g1 = thbkt(thp1);
  const float t0 = fminf(kthrG[g0], kthrG[g0+1]);
  const float t1 = fminf(kthrG[g1], kthrG[g1+1]);
  const unsigned long long ltm = (1ull << lane) - 1ull;

  unsigned cnt0 = 0, cnt1 = 0;
  {
    float al0 = acosf(clamp1((t0 + 1.00002f)*0.5f));
    float al1 = acosf(clamp1((t1 + 1.00002f)*0.5f));
    int blo = thbkt(fminf(thp0 - al0, thp1 - al1) - MG_);
    int bhi = thbkt(fmaxf(thp0 + al0, thp1 + al1) + MG_);
    int jlo = pstart[blo], jhi = pstart[bhi + 1];
    for (int base = jlo; base < jhi; base += 64) {
      int pos = base + lane;
      bool act = pos < jhi;
      float s0 = -1e30f, s1 = -1e30f;
      if (act) {
        float4 v = spix[pos];
        s0 = 2.f*(p0.x*v.x + p0.y*v.y + p0.z*v.z) - v.w;
        s1 = 2.f*(p1.x*v.x + p1.y*v.y + p1.z*v.z) - v.w;
      }
      bool pr0 = act && (pos != srow0) && (s0 > t0);
      bool pr1 = act && (pos != srow1) && (s1 > t1);
      unsigned long long mk0 = __ballot(pr0);
      if (mk0) {
        unsigned off = (unsigned)__popcll(mk0 & ltm);
        if (pr0 && cnt0 + off < KCAP) cKey[lr0][cnt0 + off] = kpack(s0, pos);
        cnt0 += (unsigned)__popcll(mk0);
      }
      unsigned long long mk1 = __ballot(pr1);
      if (mk1) {
        unsigned off = (unsigned)__popcll(mk1 & ltm);
        if (pr1 && cnt1 + off < KCAP) cKey[lr0+1][cnt1 + off] = kpack(s1, pos);
        cnt1 += (unsigned)__popcll(mk1);
      }
    }
  }

  for (int rr = 0; rr < 2; ++rr) {
    const int lr = lr0 + rr;
    const int srow = (rr == 0) ? srow0 : srow1;
    const float4 pi = (rr == 0) ? p0 : p1;
    const float thp = (rr == 0) ? thp0 : thp1;
    float th = (rr == 0) ? t0 : t1;
    unsigned cn = (rr == 0) ? cnt0 : cnt1;

    int tries = 0;
    while (cn < (unsigned)GK_ && tries < 3) {
      th = 1.6f*th - 0.6f; ++tries;
      float al = acosf(clamp1((th + 1.00002f)*0.5f));
      int blo = thbkt(thp - al - MG_), bhi = thbkt(thp + al + MG_);
      int jlo = pstart[blo], jhi = pstart[bhi + 1];
      cn = 0;
      for (int base = jlo; base < jhi; base += 64) {
        int pos = base + lane;
        bool act = pos < jhi;
        float s = -1e30f;
        if (act) {
          float4 v = spix[pos];
          s = 2.f*(pi.x*v.x + pi.y*v.y + pi.z*v.z) - v.w;
        }
        bool pr = act && (pos != srow) && (s > th);
        unsigned long long mk = __ballot(pr);
        if (mk) {
          unsigned off = (unsigned)__popcll(mk & ltm);
          if (pr && cn + off < KCAP) cKey[lr][cn + off] = kpack(s, pos);
          cn += (unsigned)__popcll(mk);
        }
      }
    }

    if (cn >= (unsigned)GK_ && cn <= (unsigned)KCAP) {
      unsigned long long pk[2];
      #pragma unroll
      for (int t2 = 0; t2 < 2; ++t2) {
        int idx = lane + 64*t2;
        pk[t2] = (idx < (int)cn) ? cKey[lr][idx] : 0ull;
      }
      for (int round = 0; round < GK_; ++round) {
        unsigned long long loc = pk[0]; int lt = 0;
        if (pk[1] > loc) { loc = pk[1]; lt = 1; }
        unsigned long long best = loc;
        #pragma unroll
        for (int off = 1; off < 64; off <<= 1) {
          unsigned long long o = shflxor64(best, off);
          best = o > best ? o : best;
        }
        if (loc == best) pk[lt] = 0ull;
        if (lane == round) nbr[srow*GK_ + round] = 16383 - (int)(best & 16383ull);
      }
    } else {
      unsigned long long prev = ~0ull;
      for (int rd = 0; rd < GK_; ++rd) {
        unsigned long long best = 0ull;
        for (int pos = lane; pos < M_; pos += 64) {
          float4 v = spix[pos];
          float s = 2.f*(pi.x*v.x + pi.y*v.y + pi.z*v.z) - v.w;
          if (pos != srow) {
            unsigned long long k = kpack(s, pos);
            if (k < prev && k > best) best = k;
          }
        }
        #pragma unroll
        for (int off = 1; off < 64; off <<= 1) {
          unsigned long long o = shflxor64(best, off);
          best = o > best ? o : best;
        }
        if (lane == rd) nbr[srow*GK_ + rd] = 16383 - (int)(best & 16383ull);
        prev = best;
      }
    }
  }
}

// ---------------- GNN layer 1 fused with proj (sorted space; XCD-swizzled; 8 rows/wave) -------
__global__ __launch_bounds__(256) void gnn1f_vO(
    const float* __restrict__ pooled, float* __restrict__ hout, const int* __restrict__ nbr,
    const float* __restrict__ pw, const float* __restrict__ pb,
    const float* __restrict__ relw, const float* __restrict__ relb,
    const float* __restrict__ rootw)
{
  __shared__ float wrel[H_*H_], wroot[H_*H_];
  const int tid = threadIdx.x;
  {
    const float4* rw4 = (const float4*)relw;
    const float4* ow4 = (const float4*)rootw;
    float4* wr4 = (float4*)wrel;
    float4* wo4 = (float4*)wroot;
    #pragma unroll
    for (int q = 0; q < 4; ++q) {
      int idx = tid + 256*q;
      wr4[idx] = rw4[idx];
      wo4[idx] = ow4[idx];
    }
  }
  __syncthreads();

  const int lane = tid & 63;
  const int wave = tid >> 6;
  const int b = blockIdx.y;
  const int bx = blockIdx.x;
  const int mblk = (bx & 7) * GCHUNK + (bx >> 3);   // XCD-contiguous m-ranges
  const int m0 = mblk * GROWS + wave * GWROWS;
  const float* pldb = pooled + (size_t)b * M_;
  const float pwl = pw[lane], pbl = pb[lane], rbl = relb[lane];

  float h[GWROWS], agg[GWROWS], acc[GWROWS];
  #pragma unroll
  for (int t = 0; t < GWROWS; ++t) {
    int m = m0 + t;
    float ps = pldb[m];
    h[t] = fmaxf(ps*pwl + pbl, 0.f);
    float a = 0.f;
    #pragma unroll
    for (int k = 0; k < GK_; ++k) {
      int nb = nbr[m*GK_ + k];
      nb = nb < 0 ? 0 : (nb >= M_ ? M_-1 : nb);
      float pn = pldb[nb];
      a += fmaxf(pn*pwl + pbl, 0.f);
    }
    agg[t] = a;
    acc[t] = rbl;
  }
  #pragma unroll
  for (int c = 0; c < H_; ++c) {
    float wr = wrel[c*H_ + lane], wo = wroot[c*H_ + lane];
    #pragma unroll
    for (int t = 0; t < GWROWS; ++t)
      acc[t] += rdlane(agg[t], c) * wr + rdlane(h[t], c) * wo;
  }
  #pragma unroll
  for (int t = 0; t < GWROWS; ++t)
    hout[((size_t)b*M_ + m0 + t)*H_ + lane] = fmaxf(acc[t], 0.f);
}

// ---------------- GNN layer (generic, sorted space; XCD-swizzled; 8 rows/wave) ---------------
__global__ __launch_bounds__(256) void gnn_vO(
    const float* __restrict__ hin, float* __restrict__ hout, const int* __restrict__ nbr,
    const float* __restrict__ relw, const float* __restrict__ relb,
    const float* __restrict__ rootw)
{
  __shared__ float wrel[H_*H_], wroot[H_*H_];
  const int tid = threadIdx.x;
  {
    const float4* rw4 = (const float4*)relw;
    const float4* ow4 = (const float4*)rootw;
    float4* wr4 = (float4*)wrel;
    float4* wo4 = (float4*)wroot;
    #pragma unroll
    for (int q = 0; q < 4; ++q) {
      int idx = tid + 256*q;
      wr4[idx] = rw4[idx];
      wo4[idx] = ow4[idx];
    }
  }
  __syncthreads();

  const int lane = tid & 63;
  const int wave = tid >> 6;
  const int b = blockIdx.y;
  const int bx = blockIdx.x;
  const int mblk = (bx & 7) * GCHUNK + (bx >> 3);
  const int m0 = mblk * GROWS + wave * GWROWS;
  const float* hb = hin + (size_t)b * M_ * H_;
  const float rbl = relb[lane];

  float h[GWROWS], agg[GWROWS], acc[GWROWS];
  #pragma unroll
  for (int t = 0; t < GWROWS; ++t) {
    int m = m0 + t;
    h[t] = hb[m*H_ + lane];
    float a = 0.f;
    #pragma unroll
    for (int k = 0; k < GK_; ++k) {
      int nb = nbr[m*GK_ + k];
      nb = nb < 0 ? 0 : (nb >= M_ ? M_-1 : nb);
      a += hb[nb*H_ + lane];
    }
    agg[t] = a;
    acc[t] = rbl;
  }
  #pragma unroll
  for (int c = 0; c < H_; ++c) {
    float wr = wrel[c*H_ + lane], wo = wroot[c*H_ + lane];
    #pragma unroll
    for (int t = 0; t < GWROWS; ++t)
      acc[t] += rdlane(agg[t], c) * wr + rdlane(h[t], c) * wo;
  }
  #pragma unroll
  for (int t = 0; t < GWROWS; ++t)
    hout[((size_t)b*M_ + m0 + t)*H_ + lane] = fmaxf(acc[t], 0.f);
}

// ---------------- GNN layer 3 + fused global-mean reduce (sorted space; XCD-swizzled) --------
__global__ __launch_bounds__(256) void gnn3r_vO(
    const float* __restrict__ hin, float* __restrict__ gf, const int* __restrict__ nbr,
    const float* __restrict__ relw, const float* __restrict__ relb,
    const float* __restrict__ rootw)
{
  __shared__ float wrel[H_*H_], wroot[H_*H_];
  __shared__ float gacc[H_];
  const int tid = threadIdx.x;
  {
    const float4* rw4 = (const float4*)relw;
    const float4* ow4 = (const float4*)rootw;
    float4* wr4 = (float4*)wrel;
    float4* wo4 = (float4*)wroot;
    #pragma unroll
    for (int q = 0; q < 4; ++q) {
      int idx = tid + 256*q;
      wr4[idx] = rw4[idx];
      wo4[idx] = ow4[idx];
    }
  }
  if (tid < H_) gacc[tid] = 0.f;
  __syncthreads();

  const int lane = tid & 63;
  const int wave = tid >> 6;
  const int b = blockIdx.y;
  const int bx = blockIdx.x;
  const int mblk = (bx & 7) * GCHUNK + (bx >> 3);
  const int m0 = mblk * GROWS + wave * GWROWS;
  const float* hb = hin + (size_t)b * M_ * H_;
  const float rbl = relb[lane];

  float h[GWROWS], agg[GWROWS], acc[GWROWS];
  #pragma unroll
  for (int t = 0; t < GWROWS; ++t) {
    int m = m0 + t;
    h[t] = hb[m*H_ + lane];
    float a = 0.f;
    #pragma unroll
    for (int k = 0; k < GK_; ++k) {
      int nb = nbr[m*GK_ + k];
      nb = nb < 0 ? 0 : (nb >= M_ ? M_-1 : nb);
      a += hb[nb*H_ + lane];
    }
    agg[t] = a;
    acc[t] = rbl;
  }
  #pragma unroll
  for (int c = 0; c < H_; ++c) {
    float wr = wrel[c*H_ + lane], wo = wroot[c*H_ + lane];
    #pragma unroll
    for (int t = 0; t < GWROWS; ++t)
      acc[t] += rdlane(agg[t], c) * wr + rdlane(h[t], c) * wo;
  }
  float ps = 0.f;
  #pragma unroll
  for (int t = 0; t < GWROWS; ++t) ps += fmaxf(acc[t], 0.f);
  atomicAdd(&gacc[lane], ps);
  __syncthreads();
  if (tid < H_) atomicAdd(&gf[b*H_ + tid], gacc[tid]);
}

// ---------------- head ----------------
__global__ __launch_bounds__(256) void head_vO(
    const float* __restrict__ gf, const float* __restrict__ w1,
    const float* __restrict__ b1, const float* __restrict__ w2,
    const float* __restrict__ b2, float* __restrict__ out)
{
  __shared__ float gfm[B_][H_], hid[B_][H_];
  const int tid = threadIdx.x;
  if (tid < B_*H_) gfm[tid >> 6][tid & 63] = gf[tid] * (1.f / (float)M_);
  __syncthreads();
  if (tid < B_*H_) {
    int b = tid >> 6, j = tid & 63;
    float acc = b1[j];
    for (int c = 0; c < H_; ++c) acc += gfm[b][c] * w1[c*H_ + j];
    hid[b][j] = fmaxf(acc, 0.f);
  }
  __syncthreads();
  for (int t = tid; t < B_*NC_; t += 256) {
    int b = t / NC_, o = t - b*NC_;
    float acc = b2[o];
    for (int j = 0; j < H_; ++j) acc += hid[b][j] * w2[j*NC_ + o];
    out[t] = acc;
  }
}

extern "C" void kernel_launch(void* const* d_in, const int* in_sizes, int n_in,
                              void* d_out, int out_size, void* d_ws, size_t ws_size,
                              hipStream_t stream)
{
  float* out = (float*)d_out;

  const size_t need = (size_t)M_*16 + (size_t)B_*N_*16 + (size_t)B_*M_*4
                    + (size_t)M_*GK_*4 + 2*(size_t)B_*M_*H_*4 + (size_t)B_*H_*4;
  bool ok_ws = ws_size >= need;
  bool ok_in = (n_in == 15) && (out_size == B_*NC_)
            && in_sizes[0] == B_*3*N_ && in_sizes[1] == M_*2
            && in_sizes[2] == 2*SH_ && in_sizes[5] == 1
            && in_sizes[8] == 3*H_*H_ && in_sizes[13] == H_*NC_;
  if (!ok_ws || !ok_in) {
    sentinel_vO<<<(out_size + 255)/256, 256, 0, stream>>>(out, out_size, ok_in ? 42.f : 43.f);
    return;
  }

  const float* xxx    = (const float*)d_in[0];
  const float* pix    = (const float*)d_in[1];
  const float* att_w1 = (const float*)d_in[2];
  const float* att_b1 = (const float*)d_in[3];
  const float* att_w2 = (const float*)d_in[4];
  const float* att_b2 = (const float*)d_in[5];
  const float* proj_w = (const float*)d_in[6];
  const float* proj_b = (const float*)d_in[7];
  const float* rel_w  = (const float*)d_in[8];
  const float* rel_b  = (const float*)d_in[9];
  const float* root_w = (const float*)d_in[10];
  const float* out_w1 = (const float*)d_in[11];
  const float* out_b1 = (const float*)d_in[12];
  const float* out_w2 = (const float*)d_in[13];
  const float* out_b2 = (const float*)d_in[14];

  char* w = (char*)d_ws;
  float4* r_pix = (float4*)w;  w += (size_t)M_ * 16;
  float4* r_los = (float4*)w;  w += (size_t)B_ * N_ * 16;
  float*  pooled = (float*)w;  w += (size_t)B_ * M_ * 4;
  int*    nbr = (int*)w;       w += (size_t)M_ * GK_ * 4;
  float*  h0 = (float*)w;      w += (size_t)B_ * M_ * H_ * 4;
  float*  h1 = (float*)w;      w += (size_t)B_ * M_ * H_ * 4;
  float*  gf = (float*)w;      w += (size_t)B_ * H_ * 4;

  // sort/threshold scratch aliases h0 (dead until gnn layer 2 writes it)
  float*  kthrG = h0;                                  // 257 grid thresholds (knn)
  float*  cthrG = h0 + 512;                            // 257 grid thresholds (sampler)
  float4* spix = (float4*)(h0 + 2*M_);                 // M float4
  int*    sjdx = (int*)(h0 + 6*M_);                    // M
  float4* slos = (float4*)(h0 + 7*M_);                 // B*N float4
  unsigned* cnt = (unsigned*)(h0 + 7*M_ + 5*B_*N_);    // 768
  int*    pstart = (int*)(cnt + 768);                  // 257
  int*    lstart = pstart + 257;                       // 2*257
  unsigned* pcur = (unsigned*)(lstart + 514);          // 256
  unsigned* lcur = pcur + 256;                         // 512

  hipMemsetAsync(cnt, 0, 768*sizeof(unsigned), stream);
  prep_vO<<<GRIDB_ + PREPB_, 256, 0, stream>>>(xxx, pix, r_pix, r_los, gf, kthrG, cthrG, cnt);
  scan_vO<<<1, 256, 0, stream>>>(cnt, pstart, lstart, pcur, lcur);
  scatter_vO<<<(M_ + B_*N_ + 255)/256, 256, 0, stream>>>(xxx, pix, r_pix, r_los, pcur, lcur,
                                                         spix, sjdx, slos);
  sampler_vO<<<dim3(M_/16, B_), 512, 0, stream>>>(pix, spix, sjdx, slos, lstart,
                                                  cthrG, att_w1, att_b1, att_w2, att_b2, pooled);
  knn_vO<<<M_/16, 512, 0, stream>>>(pix, spix, sjdx, pstart, kthrG, nbr);
  gnn1f_vO<<<dim3(GBLK, B_), 256, 0, stream>>>(pooled, h1, nbr, proj_w, proj_b,
                                               rel_w + 0*H_*H_, rel_b + 0*H_, root_w + 0*H_*H_);
  gnn_vO<<<dim3(GBLK, B_), 256, 0, stream>>>(h1, h0, nbr, rel_w + 1*H_*H_, rel_b + 1*H_, root_w + 1*H_*H_);
  gnn3r_vO<<<dim3(GBLK, B_), 256, 0, stream>>>(h0, gf, nbr, rel_w + 2*H_*H_, rel_b + 2*H_, root_w + 2*H_*H_);
  head_vO<<<1, 256, 0, stream>>>(gf, out_w1, out_b1, out_w2, out_b2, out);
}